// Round 3
// baseline (2049.174 us; speedup 1.0000x reference)
//
#include <hip/hip_runtime.h>
#include <stdint.h>
#include <math.h>

// ---------------------------------------------------------------------------
// p_net forward on MI355X.  B=4096 boards, N=81 cells, D=128, H=4 heads.
// Round 9: k_attn overhead surgery. P stays f32 in SC (PV converts hi/lo
// in-register, rinv folded into PV epilogue); V stays f32 (float4 stores);
// softmax is one pass with 4 lanes/row via shfl_xor; x pre-split to fp16
// hi/lo in k_stem (k_attn stages with direct 16B copies); QKV spread over
// all 8 waves as 36 units with B-fragment reuse; mask via packed LUT.
// Barriers per block: 33 -> 17.
// Outputs (concat, float32): pos[4096], num[4096], asc[4096*81*81].
// ---------------------------------------------------------------------------

#define NB 4096

typedef unsigned short u16;
typedef _Float16 f16x8 __attribute__((ext_vector_type(8)));
typedef float f32x4 __attribute__((ext_vector_type(4)));

__device__ __forceinline__ float silu_f(float v) {
  return v / (1.0f + expf(-v));
}

__device__ __forceinline__ float4 zero4() { return make_float4(0.f,0.f,0.f,0.f); }

__device__ __forceinline__ void fma4b(float4& a, const float s, const float4 x) {
  a.x = fmaf(s, x.x, a.x); a.y = fmaf(s, x.y, a.y);
  a.z = fmaf(s, x.z, a.z); a.w = fmaf(s, x.w, a.w);
}

__device__ __forceinline__ void dacc(float& a, const float4 w, const float4 x) {
  a = fmaf(w.x, x.x, a); a = fmaf(w.y, x.y, a);
  a = fmaf(w.z, x.z, a); a = fmaf(w.w, x.w, a);
}

// split fp32 -> fp16 hi + fp16 lo (lo scaled by 2^11 to dodge denormals)
__device__ __forceinline__ void splitu(float v, u16& h, u16& l) {
  _Float16 hf = (_Float16)v;
  _Float16 lf = (_Float16)((v - (float)hf) * 2048.0f);
  union { _Float16 f; u16 u; } a, b;
  a.f = hf; b.f = lf;
  h = a.u; l = b.u;
}

// ---------------- Threefry-2x32 (JAX partitionable) ------------------------
__device__ __forceinline__ void tf_round(uint32_t& x0, uint32_t& x1, int r) {
  x0 += x1;
  x1 = (x1 << r) | (x1 >> (32 - r));
  x1 ^= x0;
}

__device__ __forceinline__ void threefry2x32(uint32_t k0, uint32_t k1,
                                             uint32_t x0, uint32_t x1,
                                             uint32_t& o0, uint32_t& o1) {
  uint32_t k2 = k0 ^ k1 ^ 0x1BD11BDAu;
  x0 += k0; x1 += k1;
  tf_round(x0,x1,13); tf_round(x0,x1,15); tf_round(x0,x1,26); tf_round(x0,x1,6);
  x0 += k1; x1 += k2 + 1u;
  tf_round(x0,x1,17); tf_round(x0,x1,29); tf_round(x0,x1,16); tf_round(x0,x1,24);
  x0 += k2; x1 += k0 + 2u;
  tf_round(x0,x1,13); tf_round(x0,x1,15); tf_round(x0,x1,26); tf_round(x0,x1,6);
  x0 += k0; x1 += k1 + 3u;
  tf_round(x0,x1,17); tf_round(x0,x1,29); tf_round(x0,x1,16); tf_round(x0,x1,24);
  x0 += k1; x1 += k2 + 4u;
  tf_round(x0,x1,13); tf_round(x0,x1,15); tf_round(x0,x1,26); tf_round(x0,x1,6);
  x0 += k2; x1 += k0 + 5u;
  o0 = x0; o1 = x1;
}

__device__ __forceinline__ void jax_split42(uint32_t& k1a, uint32_t& k1b,
                                            uint32_t& k2a, uint32_t& k2b) {
  threefry2x32(0u, 42u, 0u, 0u, k1a, k1b);
  threefry2x32(0u, 42u, 0u, 1u, k2a, k2b);
}

__device__ __forceinline__ uint32_t jax_randbits(uint32_t ka, uint32_t kb,
                                                 uint32_t i) {
  uint32_t o0, o1;
  threefry2x32(ka, kb, 0u, i, o0, o1);
  return o0 ^ o1;
}

__device__ __forceinline__ float jax_gumbel_bits(uint32_t bits) {
  float f = __uint_as_float((bits >> 9) | 0x3f800000u) - 1.0f;
  const float tiny = 1.17549435e-38f;
  float u = fmaxf(tiny, f + tiny);
  return -logf(-logf(u));
}

// ---------------- prep: conv tables + fragment-packed conv3 weights --------
__global__ __launch_bounds__(256) void k_prep(
    const float* __restrict__ c1_w, const float* __restrict__ c1_b,
    const float* __restrict__ c2_w, const float* __restrict__ c3_w,
    const float* __restrict__ out_w, const float* __restrict__ l1_w,
    const float* __restrict__ l2_w,
    float* __restrict__ T2e, u16* __restrict__ WAh, u16* __restrict__ WAl,
    float* __restrict__ owT, float* __restrict__ l1T, float* __restrict__ l2T)
{
  int idx = blockIdx.x * 256 + threadIdx.x;
  if (idx < 9*11*128) {
    int oc = idx & 127;
    int t  = idx >> 7;
    int g  = t % 11;
    int d  = t / 11;
    float acc = 0.f;
    if (g < 10) {
      int di = d / 3, dj = d % 3;
      for (int ic = 0; ic < 64; ++ic) {
        float x1 = c1_w[ic*10 + g] + c1_b[ic];
        acc += c2_w[((oc*64 + ic)*3 + di)*3 + dj] * x1;
      }
    }
    T2e[idx] = acc;
  } else if (idx < 160128) {
    int j  = idx - 12672;          // 0..147455
    int jj = j & 7;
    int t  = j >> 3;               // ((d*4+kc)*8+ot)*64 + lane
    int ln = t & 63;
    int t2 = t >> 6;               // (d*4+kc)*8 + ot
    int ot = t2 & 7;
    int t3 = t2 >> 3;              // d*4 + kc
    int kc = t3 & 3;
    int d  = t3 >> 2;
    int oc = ot*16 + (ln & 15);
    int ic = kc*32 + (ln >> 4)*8 + jj;
    float w = c3_w[(oc*128 + ic)*9 + d];
    u16 wh, wl;
    splitu(w, wh, wl);
    WAh[j] = wh; WAl[j] = wl;
  } else if (idx < 176512) {
    int j = idx - 160128;                      // j = k*128 + oc
    owT[j] = out_w[(j & 127)*128 + (j >> 7)];
  } else if (idx < 192896) {
    int j = idx - 176512;
    l1T[j] = l1_w[(j & 127)*128 + (j >> 7)];
  } else if (idx < 209280) {
    int j = idx - 192896;
    l2T[j] = l2_w[(j & 127)*128 + (j >> 7)];
  }
}

// ---------------- stem: digits -> conv2(table, fp16 hi/lo in LDS)
//                  -> conv3 on MFMA (split-fp16) -> +emb, write x hi/lo ----
__global__ __launch_bounds__(256, 2) void k_stem(
    const float* __restrict__ s, const float* __restrict__ T2e,
    const float* __restrict__ c2_b,
    const u16* __restrict__ WAh, const u16* __restrict__ WAl,
    const float* __restrict__ c3_b, const float* __restrict__ emb,
    u16* __restrict__ xh, u16* __restrict__ xl, int* __restrict__ digits)
{
  __shared__ __align__(16) u16 x2h[121*128];   // 30976 B
  __shared__ __align__(16) u16 x2l[121*128];   // 30976 B
  __shared__ int dg[121];                      // padded digit grid, 10 = pad
  const int b   = blockIdx.x;
  const int tid = threadIdx.x;

  for (int i = tid; i < 1936; i += 256) {
    ((uint4*)x2h)[i] = make_uint4(0u,0u,0u,0u);
    ((uint4*)x2l)[i] = make_uint4(0u,0u,0u,0u);
  }
  if (tid < 121) dg[tid] = 10;
  __syncthreads();

  if (tid < 81) {
    const float* sp = s + (size_t)b*810 + tid;
    float dv = 0.f;
    #pragma unroll
    for (int c = 1; c < 10; ++c) dv += (float)c * sp[c*81];
    int d = (int)(dv + 0.5f);
    dg[(tid/9 + 1)*11 + (tid%9 + 1)] = d;
    digits[b*81 + tid] = d;
  }
  __syncthreads();

  // ---- conv2 via table: 81 cells x 16 chunks of 8 channels ----
  for (int i = tid; i < 1296; i += 256) {
    const int p  = i >> 4;
    const int k8 = i & 15;
    const int r0 = p / 9, c0 = p - r0*9;
    const float4 b0 = *(const float4*)(c2_b + k8*8);
    const float4 b1 = *(const float4*)(c2_b + k8*8 + 4);
    float a0=b0.x, a1=b0.y, a2=b0.z, a3=b0.w;
    float a4=b1.x, a5=b1.y, a6=b1.z, a7=b1.w;
    #pragma unroll
    for (int d = 0; d < 9; ++d) {
      const int g = dg[(r0 + d/3)*11 + (c0 + d%3)];
      const float* tp = T2e + (size_t)(d*11 + g)*128 + k8*8;
      const float4 t0 = *(const float4*)tp;
      const float4 t1 = *(const float4*)(tp + 4);
      a0 += t0.x; a1 += t0.y; a2 += t0.z; a3 += t0.w;
      a4 += t1.x; a5 += t1.y; a6 += t1.z; a7 += t1.w;
    }
    float v[8];
    v[0]=silu_f(a0); v[1]=silu_f(a1); v[2]=silu_f(a2); v[3]=silu_f(a3);
    v[4]=silu_f(a4); v[5]=silu_f(a5); v[6]=silu_f(a6); v[7]=silu_f(a7);
    f16x8 hv, lv;
    #pragma unroll
    for (int j = 0; j < 8; ++j) {
      _Float16 h = (_Float16)v[j];
      hv[j] = h;
      lv[j] = (_Float16)((v[j] - (float)h) * 2048.0f);
    }
    const int row = (r0 + 1)*11 + (c0 + 1);
    const uint32_t bo = (uint32_t)row*256u + (uint32_t)((k8*16) ^ ((row & 7) << 4));
    *(f16x8*)((char*)x2h + bo) = hv;
    *(f16x8*)((char*)x2l + bo) = lv;
  }
  __syncthreads();

  // ---- conv3 on MFMA ----
  const int ln  = tid & 63;
  const int wv  = tid >> 6;
  const int lg  = ln >> 4;
  const int lr  = ln & 15;
  const int otB = (wv & 1) * 4;
  const int ntB = (wv >> 1) * 3;

  f32x4 accH[4][3];
  f32x4 accC[4][3];
  #pragma unroll
  for (int ot = 0; ot < 4; ++ot)
    #pragma unroll
    for (int nt = 0; nt < 3; ++nt) {
      accH[ot][nt] = (f32x4){0.f,0.f,0.f,0.f};
      accC[ot][nt] = (f32x4){0.f,0.f,0.f,0.f};
    }

  int pbase[3];
  #pragma unroll
  for (int nt = 0; nt < 3; ++nt) {
    const int c = (ntB + nt)*16 + lr;
    pbase[nt] = (c < 81) ? (c/9)*11 + (c%9) : 0;
  }
  const char* x2hB = (const char*)x2h;
  const char* x2lB = (const char*)x2l;

  for (int d = 0; d < 9; ++d) {
    const int off = (d/3)*11 + (d - (d/3)*3);
    int rowv[3];
    #pragma unroll
    for (int nt = 0; nt < 3; ++nt) rowv[nt] = pbase[nt] + off;
    #pragma unroll
    for (int kc = 0; kc < 4; ++kc) {
      const int kb = kc*64 + lg*16;
      f16x8 Bh[3], Bl[3];
      #pragma unroll
      for (int nt = 0; nt < 3; ++nt) {
        const uint32_t o = (uint32_t)rowv[nt]*256u +
                           (uint32_t)(kb ^ ((rowv[nt] & 7) << 4));
        Bh[nt] = *(const f16x8*)(x2hB + o);
        Bl[nt] = *(const f16x8*)(x2lB + o);
      }
      const int abase = (((d*4 + kc)*8 + otB)*64 + ln)*8;
      f16x8 Ah[4], Al[4];
      #pragma unroll
      for (int ot = 0; ot < 4; ++ot) {
        Ah[ot] = *(const f16x8*)(WAh + abase + ot*512);
        Al[ot] = *(const f16x8*)(WAl + abase + ot*512);
      }
      #pragma unroll
      for (int ot = 0; ot < 4; ++ot)
        #pragma unroll
        for (int nt = 0; nt < 3; ++nt) {
          accH[ot][nt] = __builtin_amdgcn_mfma_f32_16x16x32_f16(
              Ah[ot], Bh[nt], accH[ot][nt], 0, 0, 0);
          accC[ot][nt] = __builtin_amdgcn_mfma_f32_16x16x32_f16(
              Ah[ot], Bl[nt], accC[ot][nt], 0, 0, 0);
          accC[ot][nt] = __builtin_amdgcn_mfma_f32_16x16x32_f16(
              Al[ot], Bh[nt], accC[ot][nt], 0, 0, 0);
        }
    }
  }

  // ---- epilogue: y = silu(hh + corr*2^-11 + bias) + emb -> xh/xl hi/lo ----
  #pragma unroll
  for (int nt = 0; nt < 3; ++nt) {
    const int cell = (ntB + nt)*16 + lr;
    if (cell < 81) {
      const size_t xoff = ((size_t)b*81 + cell)*128;
      #pragma unroll
      for (int ot = 0; ot < 4; ++ot) {
        const int oc = (otB + ot)*16 + lg*4;
        const float4 b3 = *(const float4*)(c3_b + oc);
        const float4 e  = *(const float4*)(emb + cell*128 + oc);
        const f32x4 hh = accH[ot][nt];
        const f32x4 cc = accC[ot][nt];
        float o0 = silu_f(hh[0] + cc[0]*(1.f/2048.f) + b3.x) + e.x;
        float o1 = silu_f(hh[1] + cc[1]*(1.f/2048.f) + b3.y) + e.y;
        float o2 = silu_f(hh[2] + cc[2]*(1.f/2048.f) + b3.z) + e.z;
        float o3 = silu_f(hh[3] + cc[3]*(1.f/2048.f) + b3.w) + e.w;
        ushort4 hv, lv;
        splitu(o0, hv.x, lv.x); splitu(o1, hv.y, lv.y);
        splitu(o2, hv.z, lv.z); splitu(o3, hv.w, lv.w);
        *(ushort4*)(xh + xoff + oc) = hv;
        *(ushort4*)(xl + xoff + oc) = lv;
      }
    }
  }
}

// ---------------- attention (MFMA, split-fp16, lean phases) ----------------
// 512 threads (8 waves) / board. LDS byte layout:
//  XH/XL  @ 0 / 24576      [96 cells][128 ch] fp16, slot^=(row&7) swizzle
//  QKH/QKL@ 49152 / 61440  [96 cells][64 m]   fp16 swizzled (q m0-31, k m32-63)
//  VF     @ 73728          [96 cells][44] f32 (v, cell-major)
//  SC     @ 90624          [96][132] f32 scores -> exp (cols 81-95 zeroed)
//  RINV   @ 141312         [96] f32
//  RCB    @ 141696         [96] u32 packed row|col<<8|box<<16
#define ATTN_LDS_BYTES 142080

__global__ __launch_bounds__(512, 1) void k_attn(
    const u16* __restrict__ xhg, const u16* __restrict__ xlg,
    const float* __restrict__ in_w, const float* __restrict__ in_b,
    float* __restrict__ ctxg, float* __restrict__ asc)
{
  extern __shared__ char smc[];
  char*  XH   = smc;
  char*  XL   = smc + 24576;
  char*  QKH  = smc + 49152;
  char*  QKL  = smc + 61440;
  float* VF   = (float*)(smc + 73728);
  float* SC   = (float*)(smc + 90624);
  float* RINV = (float*)(smc + 141312);
  uint32_t* RCB = (uint32_t*)(smc + 141696);

  const int b   = blockIdx.x;
  const int tid = threadIdx.x;
  const int ln  = tid & 63;
  const int wv  = tid >> 6;
  const int lg  = ln >> 4;
  const int lr  = ln & 15;

  if (tid < 96) {
    const int r = tid/9, c = tid - r*9;
    const int bx = (r/3)*3 + c/3;
    RCB[tid] = (uint32_t)r | ((uint32_t)c << 8) | ((uint32_t)bx << 16);
  }
  // stage x rows 0-80 (direct 16B copies), zero pad rows 81-95
  {
    const u16* gx = xhg + (size_t)b*81*128;
    const u16* gl = xlg + (size_t)b*81*128;
    for (int i = tid; i < 1296; i += 512) {
      const int n = i >> 4, k8 = i & 15;
      const uint4 hv = *(const uint4*)(gx + n*128 + k8*8);
      const uint4 lv = *(const uint4*)(gl + n*128 + k8*8);
      const uint32_t bo = (uint32_t)n*256u + ((uint32_t)(k8 ^ (n & 7)) << 4);
      *(uint4*)(XH + bo) = hv;
      *(uint4*)(XL + bo) = lv;
    }
    for (int i = tid; i < 480; i += 512) {
      char* base = (i < 240) ? XH : XL;
      const int j = (i < 240) ? i : (i - 240);
      *(uint4*)(base + 81*256 + j*16) = make_uint4(0u,0u,0u,0u);
    }
  }

  float ascR[21];
  #pragma unroll
  for (int i = 0; i < 21; ++i) ascR[i] = 0.f;

  __syncthreads();

  const int t0 = (wv*36) >> 3, t1 = ((wv + 1)*36) >> 3;

  for (int h = 0; h < 4; ++h) {
    // ---- QKV: 36 units (pu = part*2+sub 0..5, nt 0..5), u = nt*6+pu ----
    {
      int curNt = -1;
      f16x8 Bh[4], Bl[4];
      for (int u = t0; u < t1; ++u) {
        const int nt = u/6, pu = u - (u/6)*6;
        if (nt != curNt) {
          curNt = nt;
          const int row = nt*16 + lr;
          #pragma unroll
          for (int kc = 0; kc < 4; ++kc) {
            const uint32_t o = (uint32_t)row*256u +
                ((uint32_t)((kc*4 + lg) ^ (row & 7)) << 4);
            Bh[kc] = *(const f16x8*)(XH + o);
            Bl[kc] = *(const f16x8*)(XL + o);
          }
        }
        const int part = pu >> 1, sub = pu & 1;
        const int rowbase = part*128 + h*32 + sub*16;
        f32x4 aH = (f32x4){0.f,0.f,0.f,0.f};
        f32x4 aC = (f32x4){0.f,0.f,0.f,0.f};
        #pragma unroll
        for (int kc = 0; kc < 4; ++kc) {
          const float* wp = in_w + (size_t)(rowbase + lr)*128 + kc*32 + lg*8;
          f16x8 Ah, Al;
          #pragma unroll
          for (int j = 0; j < 8; ++j) {
            const float w = wp[j];
            const _Float16 hf = (_Float16)w;
            Ah[j] = hf;
            Al[j] = (_Float16)((w - (float)hf) * 2048.0f);
          }
          aH = __builtin_amdgcn_mfma_f32_16x16x32_f16(Ah, Bh[kc], aH, 0,0,0);
          aC = __builtin_amdgcn_mfma_f32_16x16x32_f16(Ah, Bl[kc], aC, 0,0,0);
          aC = __builtin_amdgcn_mfma_f32_16x16x32_f16(Al, Bh[kc], aC, 0,0,0);
        }
        const float4 bia = *(const float4*)(in_b + rowbase + lg*4);
        float v0 = aH[0] + aC[0]*(1.f/2048.f) + bia.x;
        float v1 = aH[1] + aC[1]*(1.f/2048.f) + bia.y;
        float v2 = aH[2] + aC[2]*(1.f/2048.f) + bia.z;
        float v3 = aH[3] + aC[3]*(1.f/2048.f) + bia.w;
        const int cell = nt*16 + lr;
        if (part < 2) {
          ushort4 hw, lw;
          splitu(v0, hw.x, lw.x); splitu(v1, hw.y, lw.y);
          splitu(v2, hw.z, lw.z); splitu(v3, hw.w, lw.w);
          const uint32_t b0 = (uint32_t)(part*64 + sub*32 + lg*8);
          const uint32_t ad = (uint32_t)cell*128u +
              ((((b0 >> 4) ^ (cell & 7))) << 4) + (b0 & 15);
          *(ushort4*)(QKH + ad) = hw;
          *(ushort4*)(QKL + ad) = lw;
        } else {
          *(float4*)(VF + cell*44 + sub*16 + lg*4) = make_float4(v0,v1,v2,v3);
        }
      }
    }
    __syncthreads();

    // ---- scores: 36 tiles over 8 waves ----
    {
      const uint32_t mb = (h==0) ? 0xFFu : (h==1) ? 0xFF00u
                        : (h==2) ? 0xFF0000u : 0u;
      for (int t = t0; t < t1; ++t) {
        const int qt = t/6, nt = t - (t/6)*6;
        const int ra = qt*16 + lr;
        const uint32_t oa = (uint32_t)ra*128u + ((uint32_t)(lg ^ (ra & 7)) << 4);
        const f16x8 Qh = *(const f16x8*)(QKH + oa);
        const f16x8 Ql = *(const f16x8*)(QKL + oa);
        const int rb = nt*16 + lr;
        const uint32_t ob = (uint32_t)rb*128u +
            ((uint32_t)((4 + lg) ^ (rb & 7)) << 4);
        const f16x8 Kh = *(const f16x8*)(QKH + ob);
        const f16x8 Kl = *(const f16x8*)(QKL + ob);
        f32x4 aH = (f32x4){0.f,0.f,0.f,0.f};
        f32x4 aC = (f32x4){0.f,0.f,0.f,0.f};
        aH = __builtin_amdgcn_mfma_f32_16x16x32_f16(Qh, Kh, aH, 0,0,0);
        aC = __builtin_amdgcn_mfma_f32_16x16x32_f16(Qh, Kl, aC, 0,0,0);
        aC = __builtin_amdgcn_mfma_f32_16x16x32_f16(Ql, Kh, aC, 0,0,0);
        const int kcell = nt*16 + lr;
        const uint32_t kk = RCB[kcell];
        #pragma unroll
        for (int r = 0; r < 4; ++r) {
          const int q = qt*16 + lg*4 + r;
          const uint32_t qq = RCB[q];
          const float msk = (((qq ^ kk) & mb) == 0u) ? 1.f : 0.f;
          SC[q*132 + kcell] =
              (aH[r] + aC[r]*(1.f/2048.f)) * 0.17677669529663687f + msk;
        }
      }
    }
    __syncthreads();

    // ---- softmax: 4 lanes/row, one pass, shfl reductions ----
    if (tid < 324) {
      const int row = tid >> 2, sub = tid & 3;
      float* sr = SC + row*132;
      const int kb = sub*24;
      const int ke = (sub == 3) ? 81 : kb + 24;
      float m = -1e30f;
      for (int k = kb; k < ke; ++k) m = fmaxf(m, sr[k]);
      m = fmaxf(m, __shfl_xor(m, 1));
      m = fmaxf(m, __shfl_xor(m, 2));
      float ss = 0.f;
      for (int k = kb; k < ke; ++k) {
        const float e = __expf(sr[k] - m);
        sr[k] = e;
        ss += e;
      }
      if (sub == 3) {
        #pragma unroll
        for (int k = 81; k < 96; ++k) sr[k] = 0.f;
      }
      ss += __shfl_xor(ss, 1);
      ss += __shfl_xor(ss, 2);
      if (sub == 0) RINV[row] = 1.0f / ss;
    }
    __syncthreads();

    // ---- asc accumulation (read-only on SC) ----
    #pragma unroll
    for (int i = 0; i < 21; ++i) {
      const int idx = tid + i*512;
      if (idx < 10368) {
        const int q = idx >> 7, k = idx & 127;
        if (k < 81) ascR[i] += SC[q*132 + k] * RINV[q];
      }
    }

    // ---- PV: ctx^T[hd][cell] = V^T · E, rinv in epilogue ----
    for (int t = wv; t < 12; t += 8) {
      const int ot = t/6, nt = t - (t/6)*6;
      f32x4 aH = (f32x4){0.f,0.f,0.f,0.f};
      f32x4 aC = (f32x4){0.f,0.f,0.f,0.f};
      #pragma unroll
      for (int kc = 0; kc < 3; ++kc) {
        f16x8 Ah, Al;
        #pragma unroll
        for (int j = 0; j < 8; ++j) {
          const int cellk = kc*32 + lg*8 + j;
          const float v = VF[cellk*44 + ot*16 + lr];
          const _Float16 hf = (_Float16)v;
          Ah[j] = hf;
          Al[j] = (_Float16)((v - (float)hf) * 2048.0f);
        }
        const int rb = nt*16 + lr;
        const float* pp = SC + rb*132 + kc*32 + lg*8;
        const float4 p0 = *(const float4*)pp;
        const float4 p1 = *(const float4*)(pp + 4);
        f16x8 Ph, Pl;
        {
          const float pe[8] = {p0.x,p0.y,p0.z,p0.w,p1.x,p1.y,p1.z,p1.w};
          #pragma unroll
          for (int j = 0; j < 8; ++j) {
            const _Float16 hf = (_Float16)pe[j];
            Ph[j] = hf;
            Pl[j] = (_Float16)((pe[j] - (float)hf) * 2048.0f);
          }
        }
        aH = __builtin_amdgcn_mfma_f32_16x16x32_f16(Ah, Ph, aH, 0,0,0);
        aC = __builtin_amdgcn_mfma_f32_16x16x32_f16(Ah, Pl, aC, 0,0,0);
        aC = __builtin_amdgcn_mfma_f32_16x16x32_f16(Al, Ph, aC, 0,0,0);
      }
      const int cell = nt*16 + lr;
      if (cell < 81) {
        const float rv = RINV[cell];
        float* cb = ctxg + ((size_t)b*128 + h*32 + ot*16 + lg*4)*81 + cell;
        #pragma unroll
        for (int r = 0; r < 4; ++r)
          cb[(size_t)r*81] = (aH[r] + aC[r]*(1.f/2048.f)) * rv;
      }
    }
    __syncthreads();
  } // heads

  // asc = mean over heads
  #pragma unroll
  for (int i = 0; i < 21; ++i) {
    const int idx = tid + i*512;
    if (idx < 10368) {
      const int q = idx >> 7, k = idx & 127;
      if (k < 81) asc[(size_t)b*6561 + q*81 + k] = 0.25f * ascR[i];
    }
  }
}

// ---------------- post: out-proj, LN, l1, l2, heads + sampling -------------
__global__ __launch_bounds__(256) void k_post(
    const float* __restrict__ ctxg,
    const float* __restrict__ owT,  const float* __restrict__ out_b,
    const float* __restrict__ ln_g, const float* __restrict__ ln_b,
    const float* __restrict__ l1T,  const float* __restrict__ l1_b,
    const float* __restrict__ l2T,  const float* __restrict__ l2_b,
    const float* __restrict__ pos_w, const float* __restrict__ pos_b,
    const float* __restrict__ num_w, const float* __restrict__ num_b,
    const int* __restrict__ digits,  float* __restrict__ dout)
{
  __shared__ float yT[128*84];
  __shared__ float red[243];
  __shared__ float mu[81], rstd[81];
  __shared__ float vals[81];
  __shared__ int   posIdx;
  const int b   = blockIdx.x;
  const int tid = threadIdx.x;
  const int ocg = tid >> 3;
  const int ng  = tid & 7;

  {
    const float* cb = ctxg + (size_t)b*128*81;
    for (int i = tid; i < 128*81; i += 256) {
      int k = i / 81, n = i - k*81;
      yT[k*84 + n] = cb[i];
    }
    for (int i = tid; i < 128*3; i += 256) {
      int k = i / 3, c = i - k*3;
      yT[k*84 + 81 + c] = 0.f;
    }
  }
  __syncthreads();

  // ---- out projection ----
  {
    float4 acc[4][3];
    #pragma unroll
    for (int c = 0; c < 4; ++c)
      { acc[c][0]=zero4(); acc[c][1]=zero4(); acc[c][2]=zero4(); }
    if (ng < 7) {
      #pragma unroll 2
      for (int k = 0; k < 128; ++k) {
        const float4 wv = *(const float4*)(owT + k*128 + ocg*4);
        const float* yr = yT + k*84 + ng*12;
        float4 x0 = *(const float4*)(yr);
        float4 x1 = *(const float4*)(yr + 4);
        float4 x2 = *(const float4*)(yr + 8);
        fma4b(acc[0][0], wv.x, x0); fma4b(acc[0][1], wv.x, x1); fma4b(acc[0][2], wv.x, x2);
        fma4b(acc[1][0], wv.y, x0); fma4b(acc[1][1], wv.y, x1); fma4b(acc[1][2], wv.y, x2);
        fma4b(acc[2][0], wv.z, x0); fma4b(acc[2][1], wv.z, x1); fma4b(acc[2][2], wv.z, x2);
        fma4b(acc[3][0], wv.w, x0); fma4b(acc[3][1], wv.w, x1); fma4b(acc[3][2], wv.w, x2);
      }
    }
    __syncthreads();
    if (ng < 7) {
      #pragma unroll
      for (int c = 0; c < 4; ++c) {
        const float bv = out_b[ocg*4 + c];
        #pragma unroll
        for (int t = 0; t < 3; ++t) {
          float4 o = acc[c][t];
          o.x += bv; o.y += bv; o.z += bv; o.w += bv;
          *(float4*)(yT + (ocg*4 + c)*84 + ng*12 + t*4) = o;
        }
      }
    }
  }
  __syncthreads();

  // ---- LayerNorm ----
  if (tid < 243) {
    const int n = tid/3, j = tid - (tid/3)*3;
    float ssum = 0.f;
    for (int c = 0; c < 43; ++c) {
      int k = j*43 + c;
      if (k < 128) ssum += yT[k*84 + n];
    }
    red[tid] = ssum;
  }
  __syncthreads();
  if (tid < 81)
    mu[tid] = (red[tid*3] + red[tid*3+1] + red[tid*3+2]) * (1.0f/128.0f);
  __syncthreads();
  if (tid < 243) {
    const int n = tid/3, j = tid - (tid/3)*3;
    const float m = mu[n];
    float ssum = 0.f;
    for (int c = 0; c < 43; ++c) {
      int k = j*43 + c;
      if (k < 128) { float d = yT[k*84 + n] - m; ssum += d*d; }
    }
    red[tid] = ssum;
  }
  __syncthreads();
  if (tid < 81) {
    float v = (red[tid*3] + red[tid*3+1] + red[tid*3+2]) * (1.0f/128.0f);
    rstd[tid] = 1.0f / sqrtf(v + 1e-5f);
  }
  __syncthreads();
  for (int i = tid; i < 128*81; i += 256) {
    const int k = i / 81, n = i - k*81;
    yT[k*84 + n] = (yT[k*84 + n] - mu[n]) * rstd[n] * ln_g[k] + ln_b[k];
  }
  __syncthreads();

  // ---- l1 (silu) ----
  {
    float4 acc[4][3];
    #pragma unroll
    for (int c = 0; c < 4; ++c)
      { acc[c][0]=zero4(); acc[c][1]=zero4(); acc[c][2]=zero4(); }
    if (ng < 7) {
      #pragma unroll 2
      for (int k = 0; k < 128; ++k) {
        const float4 wv = *(const float4*)(l1T + k*128 + ocg*4);
        const float* yr = yT + k*84 + ng*12;
        float4 x0 = *(const float4*)(yr);
        float4 x1 = *(const float4*)(yr + 4);
        float4 x2 = *(const float4*)(yr + 8);
        fma4b(acc[0][0], wv.x, x0); fma4b(acc[0][1], wv.x, x1); fma4b(acc[0][2], wv.x, x2);
        fma4b(acc[1][0], wv.y, x0); fma4b(acc[1][1], wv.y, x1); fma4b(acc[1][2], wv.y, x2);
        fma4b(acc[2][0], wv.z, x0); fma4b(acc[2][1], wv.z, x1); fma4b(acc[2][2], wv.z, x2);
        fma4b(acc[3][0], wv.w, x0); fma4b(acc[3][1], wv.w, x1); fma4b(acc[3][2], wv.w, x2);
      }
    }
    __syncthreads();
    if (ng < 7) {
      #pragma unroll
      for (int c = 0; c < 4; ++c) {
        const float bv = l1_b[ocg*4 + c];
        #pragma unroll
        for (int t = 0; t < 3; ++t) {
          float4 o = acc[c][t];
          o.x = silu_f(o.x + bv); o.y = silu_f(o.y + bv);
          o.z = silu_f(o.z + bv); o.w = silu_f(o.w + bv);
          *(float4*)(yT + (ocg*4 + c)*84 + ng*12 + t*4) = o;
        }
      }
    }
  }
  __syncthreads();

  // ---- l2 (silu) ----
  {
    float4 acc[4][3];
    #pragma unroll
    for (int c = 0; c < 4; ++c)
      { acc[c][0]=zero4(); acc[c][1]=zero4(); acc[c][2]=zero4(); }
    if (ng < 7) {
      #pragma unroll 2
      for (int k = 0; k < 128; ++k) {
        const float4 wv = *(const float4*)(l2T + k*128 + ocg*4);
        const float* yr = yT + k*84 + ng*12;
        float4 x0 = *(const float4*)(yr);
        float4 x1 = *(const float4*)(yr + 4);
        float4 x2 = *(const float4*)(yr + 8);
        fma4b(acc[0][0], wv.x, x0); fma4b(acc[0][1], wv.x, x1); fma4b(acc[0][2], wv.x, x2);
        fma4b(acc[1][0], wv.y, x0); fma4b(acc[1][1], wv.y, x1); fma4b(acc[1][2], wv.y, x2);
        fma4b(acc[2][0], wv.z, x0); fma4b(acc[2][1], wv.z, x1); fma4b(acc[2][2], wv.z, x2);
        fma4b(acc[3][0], wv.w, x0); fma4b(acc[3][1], wv.w, x1); fma4b(acc[3][2], wv.w, x2);
      }
    }
    __syncthreads();
    if (ng < 7) {
      #pragma unroll
      for (int c = 0; c < 4; ++c) {
        const float bv = l2_b[ocg*4 + c];
        #pragma unroll
        for (int t = 0; t < 3; ++t) {
          float4 o = acc[c][t];
          o.x = silu_f(o.x + bv); o.y = silu_f(o.y + bv);
          o.z = silu_f(o.z + bv); o.w = silu_f(o.w + bv);
          *(float4*)(yT + (ocg*4 + c)*84 + ng*12 + t*4) = o;
        }
      }
    }
  }
  __syncthreads();

  // ---- position head + gumbel sampling ----
  uint32_t k1a, k1b, k2a, k2b;
  jax_split42(k1a, k1b, k2a, k2b);

  if (tid < 243) {
    const int n = tid/3, j = tid - (tid/3)*3;
    float ssum = 0.f;
    for (int c = 0; c < 43; ++c) {
      int k = j*43 + c;
      if (k < 128) ssum += yT[k*84 + n] * pos_w[k];
    }
    red[tid] = ssum;
  }
  __syncthreads();
  if (tid < 81) {
    float acc = red[tid*3] + red[tid*3+1] + red[tid*3+2] + pos_b[0];
    if (digits[b*81 + tid] != 0) acc = -1e9f;
    uint32_t bits = jax_randbits(k1a, k1b, (uint32_t)(b*81 + tid));
    vals[tid] = acc + jax_gumbel_bits(bits);
  }
  __syncthreads();
  if (tid == 0) {
    float best = vals[0]; int bi = 0;
    for (int n = 1; n < 81; ++n)
      if (vals[n] > best) { best = vals[n]; bi = n; }
    posIdx = bi;
    dout[b] = (float)bi;
  }
  __syncthreads();
  const int pos = posIdx;

  // ---- number head at sampled position ----
  if (tid < 80) {
    const int d = tid >> 3, j = tid & 7;
    float ssum = 0.f;
    #pragma unroll
    for (int c = 0; c < 16; ++c) {
      int k = j*16 + c;
      ssum += yT[k*84 + pos] * num_w[d*128 + k];
    }
    red[tid] = ssum;
  }
  __syncthreads();
  if (tid < 10) {
    float acc = num_b[tid];
    #pragma unroll
    for (int j = 0; j < 8; ++j) acc += red[tid*8 + j];
    if (tid == 0) acc = -INFINITY;
    uint32_t bits = jax_randbits(k2a, k2b, (uint32_t)(b*10 + tid));
    vals[tid] = acc + jax_gumbel_bits(bits);
  }
  __syncthreads();
  if (tid == 0) {
    float best = vals[0]; int bi = 0;
    for (int d = 1; d < 10; ++d)
      if (vals[d] > best) { best = vals[d]; bi = d; }
    dout[NB + b] = (float)bi;
  }
}

// ---------------------------------------------------------------------------
extern "C" void kernel_launch(void* const* d_in, const int* in_sizes, int n_in,
                              void* d_out, int out_size, void* d_ws, size_t ws_size,
                              hipStream_t stream) {
  const float* s     = (const float*)d_in[0];
  const float* c1_w  = (const float*)d_in[1];
  const float* c1_b  = (const float*)d_in[2];
  const float* c2_w  = (const float*)d_in[3];
  const float* c2_b  = (const float*)d_in[4];
  const float* c3_w  = (const float*)d_in[5];
  const float* c3_b  = (const float*)d_in[6];
  const float* emb   = (const float*)d_in[7];
  const float* in_w  = (const float*)d_in[8];
  const float* in_b  = (const float*)d_in[9];
  const float* out_w = (const float*)d_in[10];
  const float* out_b = (const float*)d_in[11];
  const float* ln_g  = (const float*)d_in[12];
  const float* ln_b  = (const float*)d_in[13];
  const float* l1_w  = (const float*)d_in[14];
  const float* l1_b  = (const float*)d_in[15];
  const float* l2_w  = (const float*)d_in[16];
  const float* l2_b  = (const float*)d_in[17];
  const float* pos_w = (const float*)d_in[18];
  const float* pos_b = (const float*)d_in[19];
  const float* num_w = (const float*)d_in[20];
  const float* num_b = (const float*)d_in[21];

  // ws layout (floats):
  // T2e 0 (12672) | WAh 12672 (73728 f = 147456 u16) | WAl 86400 (73728 f) |
  // owT 160128 (16384) | l1T 176512 (16384) | l2T 192896 (16384) |
  // digits 209280 (331776 int) | xh 541056 (21233664 f as u16) |
  // xl 21774720 (21233664 f as u16) | ctxg 43008384 (42467328)
  float* ws     = (float*)d_ws;
  float* T2e    = ws;
  u16*   WAh    = (u16*)(ws + 12672);
  u16*   WAl    = (u16*)(ws + 86400);
  float* owT    = ws + 160128;
  float* l1T    = ws + 176512;
  float* l2T    = ws + 192896;
  int*   digits = (int*)(ws + 209280);
  u16*   xh     = (u16*)(ws + 541056);
  u16*   xl     = (u16*)(ws + 21774720);
  float* ctxg   = ws + 43008384;

  float* dout = (float*)d_out;
  float* asc  = dout + 2*NB;

  hipFuncSetAttribute((const void*)k_attn,
                      hipFuncAttributeMaxDynamicSharedMemorySize,
                      ATTN_LDS_BYTES);

  k_prep<<<dim3(818), dim3(256), 0, stream>>>(
      c1_w, c1_b, c2_w, c3_w, out_w, l1_w, l2_w,
      T2e, WAh, WAl, owT, l1T, l2T);
  k_stem<<<dim3(NB), dim3(256), 0, stream>>>(
      s, T2e, c2_b, WAh, WAl, c3_b, emb, xh, xl, digits);
  k_attn<<<dim3(NB), dim3(512), ATTN_LDS_BYTES, stream>>>(
      xh, xl, in_w, in_b, ctxg, asc);
  k_post<<<dim3(NB), dim3(256), 0, stream>>>(
      ctxg, owT, out_b, ln_g, ln_b, l1T, l1_b, l2T, l2_b,
      pos_w, pos_b, num_w, num_b, digits, dout);
}

// Round 4
// 1689.799 us; speedup vs baseline: 1.2127x; 1.2127x over previous
//
#include <hip/hip_runtime.h>
#include <stdint.h>
#include <math.h>

// ---------------------------------------------------------------------------
// p_net forward on MI355X.  B=4096 boards, N=81 cells, D=128, H=4 heads.
// Round 10: revert k_attn to the round-1 (864us) phase structure; deltas:
//  - 4-bit XOR swizzle (^row&15) on all 256B-row fragment buffers
//    (8-way -> 4-way bank conflicts on every ds_read_b128); QK hi/lo merged
//    into 256B rows to enable it; k_stem x2 buffers bumped likewise.
//  - P-pass writes b128 chunks (was scalar b16 pairs), skips k>=96 chunks,
//    folds asc accumulation into its read half (register double-phase, P
//    aliases SC as before).
//  - x staged from pre-split xh/xl (no splitu in staging), shfl softmax.
// Outputs (concat, float32): pos[4096], num[4096], asc[4096*81*81].
// ---------------------------------------------------------------------------

#define NB 4096

typedef unsigned short u16;
typedef _Float16 f16x8 __attribute__((ext_vector_type(8)));
typedef float f32x4 __attribute__((ext_vector_type(4)));

__device__ __forceinline__ float silu_f(float v) {
  return v / (1.0f + expf(-v));
}

__device__ __forceinline__ float4 zero4() { return make_float4(0.f,0.f,0.f,0.f); }

__device__ __forceinline__ void fma4b(float4& a, const float s, const float4 x) {
  a.x = fmaf(s, x.x, a.x); a.y = fmaf(s, x.y, a.y);
  a.z = fmaf(s, x.z, a.z); a.w = fmaf(s, x.w, a.w);
}

__device__ __forceinline__ void dacc(float& a, const float4 w, const float4 x) {
  a = fmaf(w.x, x.x, a); a = fmaf(w.y, x.y, a);
  a = fmaf(w.z, x.z, a); a = fmaf(w.w, x.w, a);
}

// split fp32 -> fp16 hi + fp16 lo (lo scaled by 2^11 to dodge denormals)
__device__ __forceinline__ void splitu(float v, u16& h, u16& l) {
  _Float16 hf = (_Float16)v;
  _Float16 lf = (_Float16)((v - (float)hf) * 2048.0f);
  union { _Float16 f; u16 u; } a, b;
  a.f = hf; b.f = lf;
  h = a.u; l = b.u;
}

// ---------------- Threefry-2x32 (JAX partitionable) ------------------------
__device__ __forceinline__ void tf_round(uint32_t& x0, uint32_t& x1, int r) {
  x0 += x1;
  x1 = (x1 << r) | (x1 >> (32 - r));
  x1 ^= x0;
}

__device__ __forceinline__ void threefry2x32(uint32_t k0, uint32_t k1,
                                             uint32_t x0, uint32_t x1,
                                             uint32_t& o0, uint32_t& o1) {
  uint32_t k2 = k0 ^ k1 ^ 0x1BD11BDAu;
  x0 += k0; x1 += k1;
  tf_round(x0,x1,13); tf_round(x0,x1,15); tf_round(x0,x1,26); tf_round(x0,x1,6);
  x0 += k1; x1 += k2 + 1u;
  tf_round(x0,x1,17); tf_round(x0,x1,29); tf_round(x0,x1,16); tf_round(x0,x1,24);
  x0 += k2; x1 += k0 + 2u;
  tf_round(x0,x1,13); tf_round(x0,x1,15); tf_round(x0,x1,26); tf_round(x0,x1,6);
  x0 += k0; x1 += k1 + 3u;
  tf_round(x0,x1,17); tf_round(x0,x1,29); tf_round(x0,x1,16); tf_round(x0,x1,24);
  x0 += k1; x1 += k2 + 4u;
  tf_round(x0,x1,13); tf_round(x0,x1,15); tf_round(x0,x1,26); tf_round(x0,x1,6);
  x0 += k2; x1 += k0 + 5u;
  o0 = x0; o1 = x1;
}

__device__ __forceinline__ void jax_split42(uint32_t& k1a, uint32_t& k1b,
                                            uint32_t& k2a, uint32_t& k2b) {
  threefry2x32(0u, 42u, 0u, 0u, k1a, k1b);
  threefry2x32(0u, 42u, 0u, 1u, k2a, k2b);
}

__device__ __forceinline__ uint32_t jax_randbits(uint32_t ka, uint32_t kb,
                                                 uint32_t i) {
  uint32_t o0, o1;
  threefry2x32(ka, kb, 0u, i, o0, o1);
  return o0 ^ o1;
}

__device__ __forceinline__ float jax_gumbel_bits(uint32_t bits) {
  float f = __uint_as_float((bits >> 9) | 0x3f800000u) - 1.0f;
  const float tiny = 1.17549435e-38f;
  float u = fmaxf(tiny, f + tiny);
  return -logf(-logf(u));
}

// ---------------- prep: conv tables + fragment-packed conv3 weights --------
__global__ __launch_bounds__(256) void k_prep(
    const float* __restrict__ c1_w, const float* __restrict__ c1_b,
    const float* __restrict__ c2_w, const float* __restrict__ c3_w,
    const float* __restrict__ out_w, const float* __restrict__ l1_w,
    const float* __restrict__ l2_w,
    float* __restrict__ T2e, u16* __restrict__ WAh, u16* __restrict__ WAl,
    float* __restrict__ owT, float* __restrict__ l1T, float* __restrict__ l2T)
{
  int idx = blockIdx.x * 256 + threadIdx.x;
  if (idx < 9*11*128) {
    int oc = idx & 127;
    int t  = idx >> 7;
    int g  = t % 11;
    int d  = t / 11;
    float acc = 0.f;
    if (g < 10) {
      int di = d / 3, dj = d % 3;
      for (int ic = 0; ic < 64; ++ic) {
        float x1 = c1_w[ic*10 + g] + c1_b[ic];
        acc += c2_w[((oc*64 + ic)*3 + di)*3 + dj] * x1;
      }
    }
    T2e[idx] = acc;
  } else if (idx < 160128) {
    int j  = idx - 12672;          // 0..147455
    int jj = j & 7;
    int t  = j >> 3;               // ((d*4+kc)*8+ot)*64 + lane
    int ln = t & 63;
    int t2 = t >> 6;               // (d*4+kc)*8 + ot
    int ot = t2 & 7;
    int t3 = t2 >> 3;              // d*4 + kc
    int kc = t3 & 3;
    int d  = t3 >> 2;
    int oc = ot*16 + (ln & 15);
    int ic = kc*32 + (ln >> 4)*8 + jj;
    float w = c3_w[(oc*128 + ic)*9 + d];
    u16 wh, wl;
    splitu(w, wh, wl);
    WAh[j] = wh; WAl[j] = wl;
  } else if (idx < 176512) {
    int j = idx - 160128;                      // j = k*128 + oc
    owT[j] = out_w[(j & 127)*128 + (j >> 7)];
  } else if (idx < 192896) {
    int j = idx - 176512;
    l1T[j] = l1_w[(j & 127)*128 + (j >> 7)];
  } else if (idx < 209280) {
    int j = idx - 192896;
    l2T[j] = l2_w[(j & 127)*128 + (j >> 7)];
  }
}

// ---------------- stem: digits -> conv2(table, fp16 hi/lo in LDS)
//                  -> conv3 on MFMA (split-fp16) -> +emb, write x hi/lo ----
// 4-bit XOR swizzle (^row&15) on x2 buffers (256B rows).
__global__ __launch_bounds__(256, 2) void k_stem(
    const float* __restrict__ s, const float* __restrict__ T2e,
    const float* __restrict__ c2_b,
    const u16* __restrict__ WAh, const u16* __restrict__ WAl,
    const float* __restrict__ c3_b, const float* __restrict__ emb,
    u16* __restrict__ xh, u16* __restrict__ xl, int* __restrict__ digits)
{
  __shared__ __align__(16) u16 x2h[121*128];   // 30976 B
  __shared__ __align__(16) u16 x2l[121*128];   // 30976 B
  __shared__ int dg[121];                      // padded digit grid, 10 = pad
  const int b   = blockIdx.x;
  const int tid = threadIdx.x;

  for (int i = tid; i < 1936; i += 256) {
    ((uint4*)x2h)[i] = make_uint4(0u,0u,0u,0u);
    ((uint4*)x2l)[i] = make_uint4(0u,0u,0u,0u);
  }
  if (tid < 121) dg[tid] = 10;
  __syncthreads();

  if (tid < 81) {
    const float* sp = s + (size_t)b*810 + tid;
    float dv = 0.f;
    #pragma unroll
    for (int c = 1; c < 10; ++c) dv += (float)c * sp[c*81];
    int d = (int)(dv + 0.5f);
    dg[(tid/9 + 1)*11 + (tid%9 + 1)] = d;
    digits[b*81 + tid] = d;
  }
  __syncthreads();

  // ---- conv2 via table: 81 cells x 16 chunks of 8 channels ----
  for (int i = tid; i < 1296; i += 256) {
    const int p  = i >> 4;
    const int k8 = i & 15;
    const int r0 = p / 9, c0 = p - r0*9;
    const float4 b0 = *(const float4*)(c2_b + k8*8);
    const float4 b1 = *(const float4*)(c2_b + k8*8 + 4);
    float a0=b0.x, a1=b0.y, a2=b0.z, a3=b0.w;
    float a4=b1.x, a5=b1.y, a6=b1.z, a7=b1.w;
    #pragma unroll
    for (int d = 0; d < 9; ++d) {
      const int g = dg[(r0 + d/3)*11 + (c0 + d%3)];
      const float* tp = T2e + (size_t)(d*11 + g)*128 + k8*8;
      const float4 t0 = *(const float4*)tp;
      const float4 t1 = *(const float4*)(tp + 4);
      a0 += t0.x; a1 += t0.y; a2 += t0.z; a3 += t0.w;
      a4 += t1.x; a5 += t1.y; a6 += t1.z; a7 += t1.w;
    }
    float v[8];
    v[0]=silu_f(a0); v[1]=silu_f(a1); v[2]=silu_f(a2); v[3]=silu_f(a3);
    v[4]=silu_f(a4); v[5]=silu_f(a5); v[6]=silu_f(a6); v[7]=silu_f(a7);
    f16x8 hv, lv;
    #pragma unroll
    for (int j = 0; j < 8; ++j) {
      _Float16 h = (_Float16)v[j];
      hv[j] = h;
      lv[j] = (_Float16)((v[j] - (float)h) * 2048.0f);
    }
    const int row = (r0 + 1)*11 + (c0 + 1);
    const uint32_t bo = (uint32_t)row*256u + ((uint32_t)(k8 ^ (row & 15)) << 4);
    *(f16x8*)((char*)x2h + bo) = hv;
    *(f16x8*)((char*)x2l + bo) = lv;
  }
  __syncthreads();

  // ---- conv3 on MFMA ----
  const int ln  = tid & 63;
  const int wv  = tid >> 6;
  const int lg  = ln >> 4;
  const int lr  = ln & 15;
  const int otB = (wv & 1) * 4;
  const int ntB = (wv >> 1) * 3;

  f32x4 accH[4][3];
  f32x4 accC[4][3];
  #pragma unroll
  for (int ot = 0; ot < 4; ++ot)
    #pragma unroll
    for (int nt = 0; nt < 3; ++nt) {
      accH[ot][nt] = (f32x4){0.f,0.f,0.f,0.f};
      accC[ot][nt] = (f32x4){0.f,0.f,0.f,0.f};
    }

  int pbase[3];
  #pragma unroll
  for (int nt = 0; nt < 3; ++nt) {
    const int c = (ntB + nt)*16 + lr;
    pbase[nt] = (c < 81) ? (c/9)*11 + (c%9) : 0;
  }
  const char* x2hB = (const char*)x2h;
  const char* x2lB = (const char*)x2l;

  for (int d = 0; d < 9; ++d) {
    const int off = (d/3)*11 + (d - (d/3)*3);
    int rowv[3];
    #pragma unroll
    for (int nt = 0; nt < 3; ++nt) rowv[nt] = pbase[nt] + off;
    #pragma unroll
    for (int kc = 0; kc < 4; ++kc) {
      f16x8 Bh[3], Bl[3];
      #pragma unroll
      for (int nt = 0; nt < 3; ++nt) {
        const uint32_t o = (uint32_t)rowv[nt]*256u +
            ((uint32_t)((kc*4 + lg) ^ (rowv[nt] & 15)) << 4);
        Bh[nt] = *(const f16x8*)(x2hB + o);
        Bl[nt] = *(const f16x8*)(x2lB + o);
      }
      const int abase = (((d*4 + kc)*8 + otB)*64 + ln)*8;
      f16x8 Ah[4], Al[4];
      #pragma unroll
      for (int ot = 0; ot < 4; ++ot) {
        Ah[ot] = *(const f16x8*)(WAh + abase + ot*512);
        Al[ot] = *(const f16x8*)(WAl + abase + ot*512);
      }
      #pragma unroll
      for (int ot = 0; ot < 4; ++ot)
        #pragma unroll
        for (int nt = 0; nt < 3; ++nt) {
          accH[ot][nt] = __builtin_amdgcn_mfma_f32_16x16x32_f16(
              Ah[ot], Bh[nt], accH[ot][nt], 0, 0, 0);
          accC[ot][nt] = __builtin_amdgcn_mfma_f32_16x16x32_f16(
              Ah[ot], Bl[nt], accC[ot][nt], 0, 0, 0);
          accC[ot][nt] = __builtin_amdgcn_mfma_f32_16x16x32_f16(
              Al[ot], Bh[nt], accC[ot][nt], 0, 0, 0);
        }
    }
  }

  // ---- epilogue: y = silu(hh + corr*2^-11 + bias) + emb -> xh/xl hi/lo ----
  #pragma unroll
  for (int nt = 0; nt < 3; ++nt) {
    const int cell = (ntB + nt)*16 + lr;
    if (cell < 81) {
      const size_t xoff = ((size_t)b*81 + cell)*128;
      #pragma unroll
      for (int ot = 0; ot < 4; ++ot) {
        const int oc = (otB + ot)*16 + lg*4;
        const float4 b3 = *(const float4*)(c3_b + oc);
        const float4 e  = *(const float4*)(emb + cell*128 + oc);
        const f32x4 hh = accH[ot][nt];
        const f32x4 cc = accC[ot][nt];
        float o0 = silu_f(hh[0] + cc[0]*(1.f/2048.f) + b3.x) + e.x;
        float o1 = silu_f(hh[1] + cc[1]*(1.f/2048.f) + b3.y) + e.y;
        float o2 = silu_f(hh[2] + cc[2]*(1.f/2048.f) + b3.z) + e.z;
        float o3 = silu_f(hh[3] + cc[3]*(1.f/2048.f) + b3.w) + e.w;
        ushort4 hv, lv;
        splitu(o0, hv.x, lv.x); splitu(o1, hv.y, lv.y);
        splitu(o2, hv.z, lv.z); splitu(o3, hv.w, lv.w);
        *(ushort4*)(xh + xoff + oc) = hv;
        *(ushort4*)(xl + xoff + oc) = lv;
      }
    }
  }
}

// ---------------- attention (MFMA, split-fp16, round-1 structure) ----------
// 512 threads (8 waves) / board. LDS byte layout:
//  XH/XL @ 0 / 24576   [96 cells][256B] fp16, slot ^= (row&15)
//  QK    @ 49152       [96 cells][256B] merged: hi slots 0-7 (q 0-3, k 4-7),
//                      lo slots 8-15; slot ^= (cell&15)
//  VTH/VTL @ 73728 / 81920  [32 hd][256B], slot ^= (hd&15)
//  SC    @ 90112       [96][132] f32 scores -> exp; aliased by PH/PL fp16
//                      probs ([96][256B] each) via register double-phase
//  RINV  @ 140800 [96]f  RCB @ 141184 [96]u32
#define ATTN_LDS_BYTES 141568

__global__ __launch_bounds__(512, 1) void k_attn(
    const u16* __restrict__ xhg, const u16* __restrict__ xlg,
    const float* __restrict__ in_w, const float* __restrict__ in_b,
    float* __restrict__ ctxg, float* __restrict__ asc)
{
  extern __shared__ char smc[];
  char*  XH   = smc;
  char*  XL   = smc + 24576;
  char*  QK   = smc + 49152;
  char*  VTH  = smc + 73728;
  char*  VTL  = smc + 81920;
  float* SC   = (float*)(smc + 90112);
  char*  PH   = smc + 90112;
  char*  PL   = smc + 114688;
  float* RINV = (float*)(smc + 140800);
  uint32_t* RCB = (uint32_t*)(smc + 141184);

  const int b   = blockIdx.x;
  const int tid = threadIdx.x;
  const int ln  = tid & 63;
  const int wv  = tid >> 6;
  const int lg  = ln >> 4;
  const int lr  = ln & 15;

  if (tid < 96) {
    const int r = tid/9, c = tid - r*9;
    const int bx = (r/3)*3 + c/3;
    RCB[tid] = (uint32_t)r | ((uint32_t)c << 8) | ((uint32_t)bx << 16);
  }
  // stage x rows 0-80 (direct 16B copies), zero pad rows 81-95
  {
    const u16* gx = xhg + (size_t)b*81*128;
    const u16* gl = xlg + (size_t)b*81*128;
    for (int i = tid; i < 1296; i += 512) {
      const int n = i >> 4, k8 = i & 15;
      const uint4 hv = *(const uint4*)(gx + n*128 + k8*8);
      const uint4 lv = *(const uint4*)(gl + n*128 + k8*8);
      const uint32_t bo = (uint32_t)n*256u + ((uint32_t)(k8 ^ (n & 15)) << 4);
      *(uint4*)(XH + bo) = hv;
      *(uint4*)(XL + bo) = lv;
    }
    for (int i = tid; i < 480; i += 512) {
      char* base = (i < 240) ? XH : XL;
      const int j = (i < 240) ? i : (i - 240);
      *(uint4*)(base + 81*256 + j*16) = make_uint4(0u,0u,0u,0u);
    }
  }

  float ascR[16];
  #pragma unroll
  for (int i = 0; i < 16; ++i) ascR[i] = 0.f;

  __syncthreads();

  for (int h = 0; h < 4; ++h) {
    // ---- QKV: waves 0-5, one 16-row otile each; W reused over 6 ntiles ----
    if (wv < 6) {
      const int part = wv >> 1;          // 0=q 1=k 2=v
      const int sub  = wv & 1;
      const int rowbase = part*128 + h*32 + sub*16;
      f32x4 accH[6], accC[6];
      #pragma unroll
      for (int nt = 0; nt < 6; ++nt) {
        accH[nt] = (f32x4){0.f,0.f,0.f,0.f};
        accC[nt] = (f32x4){0.f,0.f,0.f,0.f};
      }
      for (int kc = 0; kc < 4; ++kc) {
        const float* wp = in_w + (size_t)(rowbase + lr)*128 + kc*32 + lg*8;
        f16x8 Ah, Al;
        #pragma unroll
        for (int j = 0; j < 8; ++j) {
          const float w = wp[j];
          const _Float16 hf = (_Float16)w;
          Ah[j] = hf;
          Al[j] = (_Float16)((w - (float)hf) * 2048.0f);
        }
        #pragma unroll
        for (int nt = 0; nt < 6; ++nt) {
          const int row = nt*16 + lr;
          const uint32_t o = (uint32_t)row*256u +
              ((uint32_t)((kc*4 + lg) ^ (row & 15)) << 4);
          const f16x8 Bh = *(const f16x8*)(XH + o);
          const f16x8 Bl = *(const f16x8*)(XL + o);
          accH[nt] = __builtin_amdgcn_mfma_f32_16x16x32_f16(Ah, Bh, accH[nt], 0,0,0);
          accC[nt] = __builtin_amdgcn_mfma_f32_16x16x32_f16(Ah, Bl, accC[nt], 0,0,0);
          accC[nt] = __builtin_amdgcn_mfma_f32_16x16x32_f16(Al, Bh, accC[nt], 0,0,0);
        }
      }
      const float4 bia = *(const float4*)(in_b + rowbase + lg*4);
      #pragma unroll
      for (int nt = 0; nt < 6; ++nt) {
        const int cell = nt*16 + lr;
        float v0 = accH[nt][0] + accC[nt][0]*(1.f/2048.f) + bia.x;
        float v1 = accH[nt][1] + accC[nt][1]*(1.f/2048.f) + bia.y;
        float v2 = accH[nt][2] + accC[nt][2]*(1.f/2048.f) + bia.z;
        float v3 = accH[nt][3] + accC[nt][3]*(1.f/2048.f) + bia.w;
        if (part < 2) {
          ushort4 hw, lw;
          splitu(v0, hw.x, lw.x); splitu(v1, hw.y, lw.y);
          splitu(v2, hw.z, lw.z); splitu(v3, hw.w, lw.w);
          const int sflat = part*4 + sub*2 + (lg >> 1);   // 0..7 within hi
          const int byo   = (lg & 1)*8;
          const uint32_t adH = (uint32_t)cell*256u +
              ((uint32_t)(sflat ^ (cell & 15)) << 4) + byo;
          const uint32_t adL = (uint32_t)cell*256u +
              ((uint32_t)((8 + sflat) ^ (cell & 15)) << 4) + byo;
          *(ushort4*)(QK + adH) = hw;
          *(ushort4*)(QK + adL) = lw;
        } else {
          float vv[4] = {v0, v1, v2, v3};
          #pragma unroll
          for (int r = 0; r < 4; ++r) {
            const int hd = sub*16 + lg*4 + r;
            u16 hh, llv;
            splitu(vv[r], hh, llv);
            const uint32_t ad = (uint32_t)hd*256u +
                ((uint32_t)((cell >> 3) ^ (hd & 15)) << 4) + (cell & 7)*2;
            *(u16*)(VTH + ad) = hh;
            *(u16*)(VTL + ad) = llv;
          }
        }
      }
    }
    __syncthreads();

    // ---- scores: 36 tiles (6 qt x 6 nt) over 8 waves ----
    {
      const uint32_t mb = (h==0) ? 0xFFu : (h==1) ? 0xFF00u
                        : (h==2) ? 0xFF0000u : 0u;
      const int t0 = (wv*36) >> 3, t1 = ((wv + 1)*36) >> 3;
      for (int t = t0; t < t1; ++t) {
        const int qt = t/6, nt = t - (t/6)*6;
        const int ra = qt*16 + lr;
        const f16x8 Qh = *(const f16x8*)(QK + (uint32_t)ra*256u +
            ((uint32_t)(lg ^ (ra & 15)) << 4));
        const f16x8 Ql = *(const f16x8*)(QK + (uint32_t)ra*256u +
            ((uint32_t)((8 + lg) ^ (ra & 15)) << 4));
        const int rb = nt*16 + lr;
        const f16x8 Kh = *(const f16x8*)(QK + (uint32_t)rb*256u +
            ((uint32_t)((4 + lg) ^ (rb & 15)) << 4));
        const f16x8 Kl = *(const f16x8*)(QK + (uint32_t)rb*256u +
            ((uint32_t)((12 + lg) ^ (rb & 15)) << 4));
        f32x4 aH = (f32x4){0.f,0.f,0.f,0.f};
        f32x4 aC = (f32x4){0.f,0.f,0.f,0.f};
        aH = __builtin_amdgcn_mfma_f32_16x16x32_f16(Qh, Kh, aH, 0,0,0);
        aC = __builtin_amdgcn_mfma_f32_16x16x32_f16(Qh, Kl, aC, 0,0,0);
        aC = __builtin_amdgcn_mfma_f32_16x16x32_f16(Ql, Kh, aC, 0,0,0);
        const int kcell = nt*16 + lr;
        const uint32_t kk = RCB[kcell];
        #pragma unroll
        for (int r = 0; r < 4; ++r) {
          const int q = qt*16 + lg*4 + r;
          const uint32_t qq = RCB[q];
          const float msk = (((qq ^ kk) & mb) == 0u) ? 1.f : 0.f;
          SC[q*132 + kcell] =
              (aH[r] + aC[r]*(1.f/2048.f)) * 0.17677669529663687f + msk;
        }
      }
    }
    __syncthreads();

    // ---- softmax: 4 lanes/row, one pass, shfl reductions ----
    if (tid < 324) {
      const int row = tid >> 2, sub = tid & 3;
      float* sr = SC + row*132;
      const int kb = sub*24;
      const int ke = (sub == 3) ? 81 : kb + 24;
      float m = -1e30f;
      for (int k = kb; k < ke; ++k) m = fmaxf(m, sr[k]);
      m = fmaxf(m, __shfl_xor(m, 1));
      m = fmaxf(m, __shfl_xor(m, 2));
      float ss = 0.f;
      for (int k = kb; k < ke; ++k) {
        const float e = __expf(sr[k] - m);
        sr[k] = e;
        ss += e;
      }
      if (sub == 3) {
        #pragma unroll
        for (int k = 81; k < 96; ++k) sr[k] = 0.f;
      }
      ss += __shfl_xor(ss, 1);
      ss += __shfl_xor(ss, 2);
      if (sub == 0) RINV[row] = 1.0f / ss;
    }
    __syncthreads();

    // ---- P-pass: phase 1 read probs to regs (+asc), phase 2 write fp16 ----
    // 972 chunks: q in 0..80, k8 in 0..11 (k cells 0..95; 96+ never read)
    float pa[2][8];
    #pragma unroll
    for (int i = 0; i < 2; ++i) {
      const int idx = tid + i*512;
      if (idx < 972) {
        const int q = idx / 12, k8 = idx - q*12;
        const float rv = RINV[q];
        const float* sp = SC + q*132 + k8*8;
        const float4 p0 = *(const float4*)sp;
        const float4 p1 = *(const float4*)(sp + 4);
        pa[i][0] = p0.x*rv; pa[i][1] = p0.y*rv;
        pa[i][2] = p0.z*rv; pa[i][3] = p0.w*rv;
        pa[i][4] = p1.x*rv; pa[i][5] = p1.y*rv;
        pa[i][6] = p1.z*rv; pa[i][7] = p1.w*rv;
        #pragma unroll
        for (int j = 0; j < 8; ++j) ascR[i*8 + j] += pa[i][j];
      }
    }
    __syncthreads();
    #pragma unroll
    for (int i = 0; i < 2; ++i) {
      const int idx = tid + i*512;
      if (idx < 972) {
        const int q = idx / 12, k8 = idx - q*12;
        union { u16 u[8]; uint4 v; } hw, lw;
        #pragma unroll
        for (int j = 0; j < 8; ++j) splitu(pa[i][j], hw.u[j], lw.u[j]);
        const uint32_t ad = (uint32_t)q*256u +
            ((uint32_t)(k8 ^ (q & 15)) << 4);
        *(uint4*)(PH + ad) = hw.v;
        *(uint4*)(PL + ad) = lw.v;
      }
    }
    __syncthreads();

    // ---- PV: ctx^T[hd][cell] = V^T · P : 12 tiles (2 ot x 6 nt) ----
    for (int t = wv; t < 12; t += 8) {
      const int ot = t/6, nt = t - (t/6)*6;
      f32x4 aH = (f32x4){0.f,0.f,0.f,0.f};
      f32x4 aC = (f32x4){0.f,0.f,0.f,0.f};
      #pragma unroll
      for (int kc = 0; kc < 3; ++kc) {
        const int ra = ot*16 + lr;
        const uint32_t oa = (uint32_t)ra*256u +
            ((uint32_t)((kc*4 + lg) ^ (ra & 15)) << 4);
        const f16x8 Vh = *(const f16x8*)(VTH + oa);
        const f16x8 Vl = *(const f16x8*)(VTL + oa);
        const int rb = nt*16 + lr;
        const uint32_t ob = (uint32_t)rb*256u +
            ((uint32_t)((kc*4 + lg) ^ (rb & 15)) << 4);
        const f16x8 Pf  = *(const f16x8*)(PH + ob);
        const f16x8 Pl2 = *(const f16x8*)(PL + ob);
        aH = __builtin_amdgcn_mfma_f32_16x16x32_f16(Vh, Pf,  aH, 0,0,0);
        aC = __builtin_amdgcn_mfma_f32_16x16x32_f16(Vh, Pl2, aC, 0,0,0);
        aC = __builtin_amdgcn_mfma_f32_16x16x32_f16(Vl, Pf,  aC, 0,0,0);
      }
      const int cell = nt*16 + lr;
      if (cell < 81) {
        float* cb = ctxg + ((size_t)b*128 + h*32 + ot*16 + lg*4)*81 + cell;
        #pragma unroll
        for (int r = 0; r < 4; ++r)
          cb[(size_t)r*81] = aH[r] + aC[r]*(1.f/2048.f);
      }
    }
    __syncthreads();
  } // heads

  // asc = mean over heads
  #pragma unroll
  for (int i = 0; i < 2; ++i) {
    const int idx = tid + i*512;
    if (idx < 972) {
      const int q = idx / 12, k8 = idx - q*12;
      #pragma unroll
      for (int j = 0; j < 8; ++j) {
        const int k = k8*8 + j;
        if (k < 81) asc[(size_t)b*6561 + q*81 + k] = 0.25f * ascR[i*8 + j];
      }
    }
  }
}

// ---------------- post: out-proj, LN, l1, l2, heads + sampling -------------
__global__ __launch_bounds__(256) void k_post(
    const float* __restrict__ ctxg,
    const float* __restrict__ owT,  const float* __restrict__ out_b,
    const float* __restrict__ ln_g, const float* __restrict__ ln_b,
    const float* __restrict__ l1T,  const float* __restrict__ l1_b,
    const float* __restrict__ l2T,  const float* __restrict__ l2_b,
    const float* __restrict__ pos_w, const float* __restrict__ pos_b,
    const float* __restrict__ num_w, const float* __restrict__ num_b,
    const int* __restrict__ digits,  float* __restrict__ dout)
{
  __shared__ float yT[128*84];
  __shared__ float red[243];
  __shared__ float mu[81], rstd[81];
  __shared__ float vals[81];
  __shared__ int   posIdx;
  const int b   = blockIdx.x;
  const int tid = threadIdx.x;
  const int ocg = tid >> 3;
  const int ng  = tid & 7;

  {
    const float* cb = ctxg + (size_t)b*128*81;
    for (int i = tid; i < 128*81; i += 256) {
      int k = i / 81, n = i - k*81;
      yT[k*84 + n] = cb[i];
    }
    for (int i = tid; i < 128*3; i += 256) {
      int k = i / 3, c = i - k*3;
      yT[k*84 + 81 + c] = 0.f;
    }
  }
  __syncthreads();

  // ---- out projection ----
  {
    float4 acc[4][3];
    #pragma unroll
    for (int c = 0; c < 4; ++c)
      { acc[c][0]=zero4(); acc[c][1]=zero4(); acc[c][2]=zero4(); }
    if (ng < 7) {
      #pragma unroll 2
      for (int k = 0; k < 128; ++k) {
        const float4 wv = *(const float4*)(owT + k*128 + ocg*4);
        const float* yr = yT + k*84 + ng*12;
        float4 x0 = *(const float4*)(yr);
        float4 x1 = *(const float4*)(yr + 4);
        float4 x2 = *(const float4*)(yr + 8);
        fma4b(acc[0][0], wv.x, x0); fma4b(acc[0][1], wv.x, x1); fma4b(acc[0][2], wv.x, x2);
        fma4b(acc[1][0], wv.y, x0); fma4b(acc[1][1], wv.y, x1); fma4b(acc[1][2], wv.y, x2);
        fma4b(acc[2][0], wv.z, x0); fma4b(acc[2][1], wv.z, x1); fma4b(acc[2][2], wv.z, x2);
        fma4b(acc[3][0], wv.w, x0); fma4b(acc[3][1], wv.w, x1); fma4b(acc[3][2], wv.w, x2);
      }
    }
    __syncthreads();
    if (ng < 7) {
      #pragma unroll
      for (int c = 0; c < 4; ++c) {
        const float bv = out_b[ocg*4 + c];
        #pragma unroll
        for (int t = 0; t < 3; ++t) {
          float4 o = acc[c][t];
          o.x += bv; o.y += bv; o.z += bv; o.w += bv;
          *(float4*)(yT + (ocg*4 + c)*84 + ng*12 + t*4) = o;
        }
      }
    }
  }
  __syncthreads();

  // ---- LayerNorm ----
  if (tid < 243) {
    const int n = tid/3, j = tid - (tid/3)*3;
    float ssum = 0.f;
    for (int c = 0; c < 43; ++c) {
      int k = j*43 + c;
      if (k < 128) ssum += yT[k*84 + n];
    }
    red[tid] = ssum;
  }
  __syncthreads();
  if (tid < 81)
    mu[tid] = (red[tid*3] + red[tid*3+1] + red[tid*3+2]) * (1.0f/128.0f);
  __syncthreads();
  if (tid < 243) {
    const int n = tid/3, j = tid - (tid/3)*3;
    const float m = mu[n];
    float ssum = 0.f;
    for (int c = 0; c < 43; ++c) {
      int k = j*43 + c;
      if (k < 128) { float d = yT[k*84 + n] - m; ssum += d*d; }
    }
    red[tid] = ssum;
  }
  __syncthreads();
  if (tid < 81) {
    float v = (red[tid*3] + red[tid*3+1] + red[tid*3+2]) * (1.0f/128.0f);
    rstd[tid] = 1.0f / sqrtf(v + 1e-5f);
  }
  __syncthreads();
  for (int i = tid; i < 128*81; i += 256) {
    const int k = i / 81, n = i - k*81;
    yT[k*84 + n] = (yT[k*84 + n] - mu[n]) * rstd[n] * ln_g[k] + ln_b[k];
  }
  __syncthreads();

  // ---- l1 (silu) ----
  {
    float4 acc[4][3];
    #pragma unroll
    for (int c = 0; c < 4; ++c)
      { acc[c][0]=zero4(); acc[c][1]=zero4(); acc[c][2]=zero4(); }
    if (ng < 7) {
      #pragma unroll 2
      for (int k = 0; k < 128; ++k) {
        const float4 wv = *(const float4*)(l1T + k*128 + ocg*4);
        const float* yr = yT + k*84 + ng*12;
        float4 x0 = *(const float4*)(yr);
        float4 x1 = *(const float4*)(yr + 4);
        float4 x2 = *(const float4*)(yr + 8);
        fma4b(acc[0][0], wv.x, x0); fma4b(acc[0][1], wv.x, x1); fma4b(acc[0][2], wv.x, x2);
        fma4b(acc[1][0], wv.y, x0); fma4b(acc[1][1], wv.y, x1); fma4b(acc[1][2], wv.y, x2);
        fma4b(acc[2][0], wv.z, x0); fma4b(acc[2][1], wv.z, x1); fma4b(acc[2][2], wv.z, x2);
        fma4b(acc[3][0], wv.w, x0); fma4b(acc[3][1], wv.w, x1); fma4b(acc[3][2], wv.w, x2);
      }
    }
    __syncthreads();
    if (ng < 7) {
      #pragma unroll
      for (int c = 0; c < 4; ++c) {
        const float bv = l1_b[ocg*4 + c];
        #pragma unroll
        for (int t = 0; t < 3; ++t) {
          float4 o = acc[c][t];
          o.x = silu_f(o.x + bv); o.y = silu_f(o.y + bv);
          o.z = silu_f(o.z + bv); o.w = silu_f(o.w + bv);
          *(float4*)(yT + (ocg*4 + c)*84 + ng*12 + t*4) = o;
        }
      }
    }
  }
  __syncthreads();

  // ---- l2 (silu) ----
  {
    float4 acc[4][3];
    #pragma unroll
    for (int c = 0; c < 4; ++c)
      { acc[c][0]=zero4(); acc[c][1]=zero4(); acc[c][2]=zero4(); }
    if (ng < 7) {
      #pragma unroll 2
      for (int k = 0; k < 128; ++k) {
        const float4 wv = *(const float4*)(l2T + k*128 + ocg*4);
        const float* yr = yT + k*84 + ng*12;
        float4 x0 = *(const float4*)(yr);
        float4 x1 = *(const float4*)(yr + 4);
        float4 x2 = *(const float4*)(yr + 8);
        fma4b(acc[0][0], wv.x, x0); fma4b(acc[0][1], wv.x, x1); fma4b(acc[0][2], wv.x, x2);
        fma4b(acc[1][0], wv.y, x0); fma4b(acc[1][1], wv.y, x1); fma4b(acc[1][2], wv.y, x2);
        fma4b(acc[2][0], wv.z, x0); fma4b(acc[2][1], wv.z, x1); fma4b(acc[2][2], wv.z, x2);
        fma4b(acc[3][0], wv.w, x0); fma4b(acc[3][1], wv.w, x1); fma4b(acc[3][2], wv.w, x2);
      }
    }
    __syncthreads();
    if (ng < 7) {
      #pragma unroll
      for (int c = 0; c < 4; ++c) {
        const float bv = l2_b[ocg*4 + c];
        #pragma unroll
        for (int t = 0; t < 3; ++t) {
          float4 o = acc[c][t];
          o.x = silu_f(o.x + bv); o.y = silu_f(o.y + bv);
          o.z = silu_f(o.z + bv); o.w = silu_f(o.w + bv);
          *(float4*)(yT + (ocg*4 + c)*84 + ng*12 + t*4) = o;
        }
      }
    }
  }
  __syncthreads();

  // ---- position head + gumbel sampling ----
  uint32_t k1a, k1b, k2a, k2b;
  jax_split42(k1a, k1b, k2a, k2b);

  if (tid < 243) {
    const int n = tid/3, j = tid - (tid/3)*3;
    float ssum = 0.f;
    for (int c = 0; c < 43; ++c) {
      int k = j*43 + c;
      if (k < 128) ssum += yT[k*84 + n] * pos_w[k];
    }
    red[tid] = ssum;
  }
  __syncthreads();
  if (tid < 81) {
    float acc = red[tid*3] + red[tid*3+1] + red[tid*3+2] + pos_b[0];
    if (digits[b*81 + tid] != 0) acc = -1e9f;
    uint32_t bits = jax_randbits(k1a, k1b, (uint32_t)(b*81 + tid));
    vals[tid] = acc + jax_gumbel_bits(bits);
  }
  __syncthreads();
  if (tid == 0) {
    float best = vals[0]; int bi = 0;
    for (int n = 1; n < 81; ++n)
      if (vals[n] > best) { best = vals[n]; bi = n; }
    posIdx = bi;
    dout[b] = (float)bi;
  }
  __syncthreads();
  const int pos = posIdx;

  // ---- number head at sampled position ----
  if (tid < 80) {
    const int d = tid >> 3, j = tid & 7;
    float ssum = 0.f;
    #pragma unroll
    for (int c = 0; c < 16; ++c) {
      int k = j*16 + c;
      ssum += yT[k*84 + pos] * num_w[d*128 + k];
    }
    red[tid] = ssum;
  }
  __syncthreads();
  if (tid < 10) {
    float acc = num_b[tid];
    #pragma unroll
    for (int j = 0; j < 8; ++j) acc += red[tid*8 + j];
    if (tid == 0) acc = -INFINITY;
    uint32_t bits = jax_randbits(k2a, k2b, (uint32_t)(b*10 + tid));
    vals[tid] = acc + jax_gumbel_bits(bits);
  }
  __syncthreads();
  if (tid == 0) {
    float best = vals[0]; int bi = 0;
    for (int d = 1; d < 10; ++d)
      if (vals[d] > best) { best = vals[d]; bi = d; }
    dout[NB + b] = (float)bi;
  }
}

// ---------------------------------------------------------------------------
extern "C" void kernel_launch(void* const* d_in, const int* in_sizes, int n_in,
                              void* d_out, int out_size, void* d_ws, size_t ws_size,
                              hipStream_t stream) {
  const float* s     = (const float*)d_in[0];
  const float* c1_w  = (const float*)d_in[1];
  const float* c1_b  = (const float*)d_in[2];
  const float* c2_w  = (const float*)d_in[3];
  const float* c2_b  = (const float*)d_in[4];
  const float* c3_w  = (const float*)d_in[5];
  const float* c3_b  = (const float*)d_in[6];
  const float* emb   = (const float*)d_in[7];
  const float* in_w  = (const float*)d_in[8];
  const float* in_b  = (const float*)d_in[9];
  const float* out_w = (const float*)d_in[10];
  const float* out_b = (const float*)d_in[11];
  const float* ln_g  = (const float*)d_in[12];
  const float* ln_b  = (const float*)d_in[13];
  const float* l1_w  = (const float*)d_in[14];
  const float* l1_b  = (const float*)d_in[15];
  const float* l2_w  = (const float*)d_in[16];
  const float* l2_b  = (const float*)d_in[17];
  const float* pos_w = (const float*)d_in[18];
  const float* pos_b = (const float*)d_in[19];
  const float* num_w = (const float*)d_in[20];
  const float* num_b = (const float*)d_in[21];

  // ws layout (floats):
  // T2e 0 (12672) | WAh 12672 (73728 f = 147456 u16) | WAl 86400 (73728 f) |
  // owT 160128 (16384) | l1T 176512 (16384) | l2T 192896 (16384) |
  // digits 209280 (331776 int) | xh 541056 (u16) | xl 21774720 (u16) |
  // ctxg 43008384
  float* ws     = (float*)d_ws;
  float* T2e    = ws;
  u16*   WAh    = (u16*)(ws + 12672);
  u16*   WAl    = (u16*)(ws + 86400);
  float* owT    = ws + 160128;
  float* l1T    = ws + 176512;
  float* l2T    = ws + 192896;
  int*   digits = (int*)(ws + 209280);
  u16*   xh     = (u16*)(ws + 541056);
  u16*   xl     = (u16*)(ws + 21774720);
  float* ctxg   = ws + 43008384;

  float* dout = (float*)d_out;
  float* asc  = dout + 2*NB;

  hipFuncSetAttribute((const void*)k_attn,
                      hipFuncAttributeMaxDynamicSharedMemorySize,
                      ATTN_LDS_BYTES);

  k_prep<<<dim3(818), dim3(256), 0, stream>>>(
      c1_w, c1_b, c2_w, c3_w, out_w, l1_w, l2_w,
      T2e, WAh, WAl, owT, l1T, l2T);
  k_stem<<<dim3(NB), dim3(256), 0, stream>>>(
      s, T2e, c2_b, WAh, WAl, c3_b, emb, xh, xl, digits);
  k_attn<<<dim3(NB), dim3(512), ATTN_LDS_BYTES, stream>>>(
      xh, xl, in_w, in_b, ctxg, asc);
  k_post<<<dim3(NB), dim3(256), 0, stream>>>(
      ctxg, owT, out_b, ln_g, ln_b, l1T, l1_b, l2T, l2_b,
      pos_w, pos_b, num_w, num_b, digits, dout);
}

// Round 5
// 1440.110 us; speedup vs baseline: 1.4229x; 1.1734x over previous
//
#include <hip/hip_runtime.h>
#include <stdint.h>
#include <math.h>

// ---------------------------------------------------------------------------
// p_net forward on MI355X.  B=4096 boards, N=81 cells, D=128, H=4 heads.
// Round 11: k_post moved to MFMA (mfma_f32_16x16x32_f16, split-fp16 hi/lo —
// third application of the validated recipe). k_attn PV epilogue emits ctx
// pre-split hi/lo u16 [b][cell][128] (ushort4 stores); k_post stages with
// direct 16B copies. out_w/l1_w/l2_w fragment-packed hi/lo in k_prep
// (same ws slots). k_post: 8 waves, GEMM->LN(2-pass)->GEMM->GEMM ping-pong
// between swizzled hi/lo LDS buffers; pos-head fused into l2 epilogue.
// Outputs (concat, float32): pos[4096], num[4096], asc[4096*81*81].
// ---------------------------------------------------------------------------

#define NB 4096

typedef unsigned short u16;
typedef _Float16 f16x8 __attribute__((ext_vector_type(8)));
typedef float f32x4 __attribute__((ext_vector_type(4)));

__device__ __forceinline__ float silu_f(float v) {
  return v / (1.0f + expf(-v));
}

// split fp32 -> fp16 hi + fp16 lo (lo scaled by 2^11 to dodge denormals)
__device__ __forceinline__ void splitu(float v, u16& h, u16& l) {
  _Float16 hf = (_Float16)v;
  _Float16 lf = (_Float16)((v - (float)hf) * 2048.0f);
  union { _Float16 f; u16 u; } a, b;
  a.f = hf; b.f = lf;
  h = a.u; l = b.u;
}

__device__ __forceinline__ float joinu(u16 h, u16 l) {
  union { u16 u; _Float16 f; } a, b;
  a.u = h; b.u = l;
  return (float)a.f + (float)b.f * (1.f/2048.f);
}

// ---------------- Threefry-2x32 (JAX partitionable) ------------------------
__device__ __forceinline__ void tf_round(uint32_t& x0, uint32_t& x1, int r) {
  x0 += x1;
  x1 = (x1 << r) | (x1 >> (32 - r));
  x1 ^= x0;
}

__device__ __forceinline__ void threefry2x32(uint32_t k0, uint32_t k1,
                                             uint32_t x0, uint32_t x1,
                                             uint32_t& o0, uint32_t& o1) {
  uint32_t k2 = k0 ^ k1 ^ 0x1BD11BDAu;
  x0 += k0; x1 += k1;
  tf_round(x0,x1,13); tf_round(x0,x1,15); tf_round(x0,x1,26); tf_round(x0,x1,6);
  x0 += k1; x1 += k2 + 1u;
  tf_round(x0,x1,17); tf_round(x0,x1,29); tf_round(x0,x1,16); tf_round(x0,x1,24);
  x0 += k2; x1 += k0 + 2u;
  tf_round(x0,x1,13); tf_round(x0,x1,15); tf_round(x0,x1,26); tf_round(x0,x1,6);
  x0 += k0; x1 += k1 + 3u;
  tf_round(x0,x1,17); tf_round(x0,x1,29); tf_round(x0,x1,16); tf_round(x0,x1,24);
  x0 += k1; x1 += k2 + 4u;
  tf_round(x0,x1,13); tf_round(x0,x1,15); tf_round(x0,x1,26); tf_round(x0,x1,6);
  x0 += k2; x1 += k0 + 5u;
  o0 = x0; o1 = x1;
}

__device__ __forceinline__ void jax_split42(uint32_t& k1a, uint32_t& k1b,
                                            uint32_t& k2a, uint32_t& k2b) {
  threefry2x32(0u, 42u, 0u, 0u, k1a, k1b);
  threefry2x32(0u, 42u, 0u, 1u, k2a, k2b);
}

__device__ __forceinline__ uint32_t jax_randbits(uint32_t ka, uint32_t kb,
                                                 uint32_t i) {
  uint32_t o0, o1;
  threefry2x32(ka, kb, 0u, i, o0, o1);
  return o0 ^ o1;
}

__device__ __forceinline__ float jax_gumbel_bits(uint32_t bits) {
  float f = __uint_as_float((bits >> 9) | 0x3f800000u) - 1.0f;
  const float tiny = 1.17549435e-38f;
  float u = fmaxf(tiny, f + tiny);
  return -logf(-logf(u));
}

// ---------------- prep: conv tables + fragment-packed weights --------------
// WAh/WAl (conv3): [(d*4+kc)*8 + ot][lane][j].  WO/W1/W2: [(kc*8+ot)][lane][j].
// Fragment semantics: m = lane&15 (oc), k = kc*32 + (lane>>4)*8 + j.
__global__ __launch_bounds__(256) void k_prep(
    const float* __restrict__ c1_w, const float* __restrict__ c1_b,
    const float* __restrict__ c2_w, const float* __restrict__ c3_w,
    const float* __restrict__ out_w, const float* __restrict__ l1_w,
    const float* __restrict__ l2_w,
    float* __restrict__ T2e, u16* __restrict__ WAh, u16* __restrict__ WAl,
    u16* __restrict__ WOh, u16* __restrict__ W1h, u16* __restrict__ W2h)
{
  int idx = blockIdx.x * 256 + threadIdx.x;
  if (idx < 9*11*128) {
    int oc = idx & 127;
    int t  = idx >> 7;
    int g  = t % 11;
    int d  = t / 11;
    float acc = 0.f;
    if (g < 10) {
      int di = d / 3, dj = d % 3;
      for (int ic = 0; ic < 64; ++ic) {
        float x1 = c1_w[ic*10 + g] + c1_b[ic];
        acc += c2_w[((oc*64 + ic)*3 + di)*3 + dj] * x1;
      }
    }
    T2e[idx] = acc;
  } else if (idx < 160128) {
    int j  = idx - 12672;          // 0..147455
    int jj = j & 7;
    int t  = j >> 3;               // ((d*4+kc)*8+ot)*64 + lane
    int ln = t & 63;
    int t2 = t >> 6;               // (d*4+kc)*8 + ot
    int ot = t2 & 7;
    int t3 = t2 >> 3;              // d*4 + kc
    int kc = t3 & 3;
    int d  = t3 >> 2;
    int oc = ot*16 + (ln & 15);
    int ic = kc*32 + (ln >> 4)*8 + jj;
    float w = c3_w[(oc*128 + ic)*9 + d];
    u16 wh, wl;
    splitu(w, wh, wl);
    WAh[j] = wh; WAl[j] = wl;
  } else if (idx < 209280) {
    int j = idx - 160128;          // 0..49151 over 3 matrices
    int mi = j >> 14;              // 0..2
    int jr = j & 16383;
    int jj = jr & 7;
    int t  = jr >> 3;
    int ln = t & 63;
    int t2 = t >> 6;               // kc*8 + ot
    int ot = t2 & 7;
    int kc = t2 >> 3;
    int oc = ot*16 + (ln & 15);
    int k  = kc*32 + (ln >> 4)*8 + jj;
    const float* W = (mi == 0) ? out_w : (mi == 1) ? l1_w : l2_w;
    u16* Dh = (mi == 0) ? WOh : (mi == 1) ? W1h : W2h;
    u16 wh, wl;
    splitu(W[oc*128 + k], wh, wl);
    Dh[jr] = wh; Dh[16384 + jr] = wl;
  }
}

// ---------------- stem: digits -> conv2(table, fp16 hi/lo in LDS)
//                  -> conv3 on MFMA (split-fp16) -> +emb, write x hi/lo ----
__global__ __launch_bounds__(256, 2) void k_stem(
    const float* __restrict__ s, const float* __restrict__ T2e,
    const float* __restrict__ c2_b,
    const u16* __restrict__ WAh, const u16* __restrict__ WAl,
    const float* __restrict__ c3_b, const float* __restrict__ emb,
    u16* __restrict__ xh, u16* __restrict__ xl, int* __restrict__ digits)
{
  __shared__ __align__(16) u16 x2h[121*128];   // 30976 B
  __shared__ __align__(16) u16 x2l[121*128];   // 30976 B
  __shared__ int dg[121];                      // padded digit grid, 10 = pad
  const int b   = blockIdx.x;
  const int tid = threadIdx.x;

  for (int i = tid; i < 1936; i += 256) {
    ((uint4*)x2h)[i] = make_uint4(0u,0u,0u,0u);
    ((uint4*)x2l)[i] = make_uint4(0u,0u,0u,0u);
  }
  if (tid < 121) dg[tid] = 10;
  __syncthreads();

  if (tid < 81) {
    const float* sp = s + (size_t)b*810 + tid;
    float dv = 0.f;
    #pragma unroll
    for (int c = 1; c < 10; ++c) dv += (float)c * sp[c*81];
    int d = (int)(dv + 0.5f);
    dg[(tid/9 + 1)*11 + (tid%9 + 1)] = d;
    digits[b*81 + tid] = d;
  }
  __syncthreads();

  // ---- conv2 via table: 81 cells x 16 chunks of 8 channels ----
  for (int i = tid; i < 1296; i += 256) {
    const int p  = i >> 4;
    const int k8 = i & 15;
    const int r0 = p / 9, c0 = p - r0*9;
    const float4 b0 = *(const float4*)(c2_b + k8*8);
    const float4 b1 = *(const float4*)(c2_b + k8*8 + 4);
    float a0=b0.x, a1=b0.y, a2=b0.z, a3=b0.w;
    float a4=b1.x, a5=b1.y, a6=b1.z, a7=b1.w;
    #pragma unroll
    for (int d = 0; d < 9; ++d) {
      const int g = dg[(r0 + d/3)*11 + (c0 + d%3)];
      const float* tp = T2e + (size_t)(d*11 + g)*128 + k8*8;
      const float4 t0 = *(const float4*)tp;
      const float4 t1 = *(const float4*)(tp + 4);
      a0 += t0.x; a1 += t0.y; a2 += t0.z; a3 += t0.w;
      a4 += t1.x; a5 += t1.y; a6 += t1.z; a7 += t1.w;
    }
    float v[8];
    v[0]=silu_f(a0); v[1]=silu_f(a1); v[2]=silu_f(a2); v[3]=silu_f(a3);
    v[4]=silu_f(a4); v[5]=silu_f(a5); v[6]=silu_f(a6); v[7]=silu_f(a7);
    f16x8 hv, lv;
    #pragma unroll
    for (int j = 0; j < 8; ++j) {
      _Float16 h = (_Float16)v[j];
      hv[j] = h;
      lv[j] = (_Float16)((v[j] - (float)h) * 2048.0f);
    }
    const int row = (r0 + 1)*11 + (c0 + 1);
    const uint32_t bo = (uint32_t)row*256u + ((uint32_t)(k8 ^ (row & 15)) << 4);
    *(f16x8*)((char*)x2h + bo) = hv;
    *(f16x8*)((char*)x2l + bo) = lv;
  }
  __syncthreads();

  // ---- conv3 on MFMA ----
  const int ln  = tid & 63;
  const int wv  = tid >> 6;
  const int lg  = ln >> 4;
  const int lr  = ln & 15;
  const int otB = (wv & 1) * 4;
  const int ntB = (wv >> 1) * 3;

  f32x4 accH[4][3];
  f32x4 accC[4][3];
  #pragma unroll
  for (int ot = 0; ot < 4; ++ot)
    #pragma unroll
    for (int nt = 0; nt < 3; ++nt) {
      accH[ot][nt] = (f32x4){0.f,0.f,0.f,0.f};
      accC[ot][nt] = (f32x4){0.f,0.f,0.f,0.f};
    }

  int pbase[3];
  #pragma unroll
  for (int nt = 0; nt < 3; ++nt) {
    const int c = (ntB + nt)*16 + lr;
    pbase[nt] = (c < 81) ? (c/9)*11 + (c%9) : 0;
  }
  const char* x2hB = (const char*)x2h;
  const char* x2lB = (const char*)x2l;

  for (int d = 0; d < 9; ++d) {
    const int off = (d/3)*11 + (d - (d/3)*3);
    int rowv[3];
    #pragma unroll
    for (int nt = 0; nt < 3; ++nt) rowv[nt] = pbase[nt] + off;
    #pragma unroll
    for (int kc = 0; kc < 4; ++kc) {
      f16x8 Bh[3], Bl[3];
      #pragma unroll
      for (int nt = 0; nt < 3; ++nt) {
        const uint32_t o = (uint32_t)rowv[nt]*256u +
            ((uint32_t)((kc*4 + lg) ^ (rowv[nt] & 15)) << 4);
        Bh[nt] = *(const f16x8*)(x2hB + o);
        Bl[nt] = *(const f16x8*)(x2lB + o);
      }
      const int abase = (((d*4 + kc)*8 + otB)*64 + ln)*8;
      f16x8 Ah[4], Al[4];
      #pragma unroll
      for (int ot = 0; ot < 4; ++ot) {
        Ah[ot] = *(const f16x8*)(WAh + abase + ot*512);
        Al[ot] = *(const f16x8*)(WAl + abase + ot*512);
      }
      #pragma unroll
      for (int ot = 0; ot < 4; ++ot)
        #pragma unroll
        for (int nt = 0; nt < 3; ++nt) {
          accH[ot][nt] = __builtin_amdgcn_mfma_f32_16x16x32_f16(
              Ah[ot], Bh[nt], accH[ot][nt], 0, 0, 0);
          accC[ot][nt] = __builtin_amdgcn_mfma_f32_16x16x32_f16(
              Ah[ot], Bl[nt], accC[ot][nt], 0, 0, 0);
          accC[ot][nt] = __builtin_amdgcn_mfma_f32_16x16x32_f16(
              Al[ot], Bh[nt], accC[ot][nt], 0, 0, 0);
        }
    }
  }

  // ---- epilogue: y = silu(hh + corr*2^-11 + bias) + emb -> xh/xl hi/lo ----
  #pragma unroll
  for (int nt = 0; nt < 3; ++nt) {
    const int cell = (ntB + nt)*16 + lr;
    if (cell < 81) {
      const size_t xoff = ((size_t)b*81 + cell)*128;
      #pragma unroll
      for (int ot = 0; ot < 4; ++ot) {
        const int oc = (otB + ot)*16 + lg*4;
        const float4 b3 = *(const float4*)(c3_b + oc);
        const float4 e  = *(const float4*)(emb + cell*128 + oc);
        const f32x4 hh = accH[ot][nt];
        const f32x4 cc = accC[ot][nt];
        float o0 = silu_f(hh[0] + cc[0]*(1.f/2048.f) + b3.x) + e.x;
        float o1 = silu_f(hh[1] + cc[1]*(1.f/2048.f) + b3.y) + e.y;
        float o2 = silu_f(hh[2] + cc[2]*(1.f/2048.f) + b3.z) + e.z;
        float o3 = silu_f(hh[3] + cc[3]*(1.f/2048.f) + b3.w) + e.w;
        ushort4 hv, lv;
        splitu(o0, hv.x, lv.x); splitu(o1, hv.y, lv.y);
        splitu(o2, hv.z, lv.z); splitu(o3, hv.w, lv.w);
        *(ushort4*)(xh + xoff + oc) = hv;
        *(ushort4*)(xl + xoff + oc) = lv;
      }
    }
  }
}

// ---------------- attention (MFMA, split-fp16) -----------------------------
// Unchanged from round 10 except PV epilogue writes ctx as hi/lo u16
// [b][cell][128] (ushort4 stores).
#define ATTN_LDS_BYTES 141568

__global__ __launch_bounds__(512, 1) void k_attn(
    const u16* __restrict__ xhg, const u16* __restrict__ xlg,
    const float* __restrict__ in_w, const float* __restrict__ in_b,
    u16* __restrict__ ctxh, u16* __restrict__ ctxl, float* __restrict__ asc)
{
  extern __shared__ char smc[];
  char*  XH   = smc;
  char*  XL   = smc + 24576;
  char*  QK   = smc + 49152;
  char*  VTH  = smc + 73728;
  char*  VTL  = smc + 81920;
  float* SC   = (float*)(smc + 90112);
  char*  PH   = smc + 90112;
  char*  PL   = smc + 114688;
  float* RINV = (float*)(smc + 140800);
  uint32_t* RCB = (uint32_t*)(smc + 141184);

  const int b   = blockIdx.x;
  const int tid = threadIdx.x;
  const int ln  = tid & 63;
  const int wv  = tid >> 6;
  const int lg  = ln >> 4;
  const int lr  = ln & 15;

  if (tid < 96) {
    const int r = tid/9, c = tid - r*9;
    const int bx = (r/3)*3 + c/3;
    RCB[tid] = (uint32_t)r | ((uint32_t)c << 8) | ((uint32_t)bx << 16);
  }
  // stage x rows 0-80 (direct 16B copies), zero pad rows 81-95
  {
    const u16* gx = xhg + (size_t)b*81*128;
    const u16* gl = xlg + (size_t)b*81*128;
    for (int i = tid; i < 1296; i += 512) {
      const int n = i >> 4, k8 = i & 15;
      const uint4 hv = *(const uint4*)(gx + n*128 + k8*8);
      const uint4 lv = *(const uint4*)(gl + n*128 + k8*8);
      const uint32_t bo = (uint32_t)n*256u + ((uint32_t)(k8 ^ (n & 15)) << 4);
      *(uint4*)(XH + bo) = hv;
      *(uint4*)(XL + bo) = lv;
    }
    for (int i = tid; i < 480; i += 512) {
      char* base = (i < 240) ? XH : XL;
      const int j = (i < 240) ? i : (i - 240);
      *(uint4*)(base + 81*256 + j*16) = make_uint4(0u,0u,0u,0u);
    }
  }

  float ascR[16];
  #pragma unroll
  for (int i = 0; i < 16; ++i) ascR[i] = 0.f;

  __syncthreads();

  for (int h = 0; h < 4; ++h) {
    // ---- QKV: waves 0-5, one 16-row otile each; W reused over 6 ntiles ----
    if (wv < 6) {
      const int part = wv >> 1;          // 0=q 1=k 2=v
      const int sub  = wv & 1;
      const int rowbase = part*128 + h*32 + sub*16;
      f32x4 accH[6], accC[6];
      #pragma unroll
      for (int nt = 0; nt < 6; ++nt) {
        accH[nt] = (f32x4){0.f,0.f,0.f,0.f};
        accC[nt] = (f32x4){0.f,0.f,0.f,0.f};
      }
      for (int kc = 0; kc < 4; ++kc) {
        const float* wp = in_w + (size_t)(rowbase + lr)*128 + kc*32 + lg*8;
        f16x8 Ah, Al;
        #pragma unroll
        for (int j = 0; j < 8; ++j) {
          const float w = wp[j];
          const _Float16 hf = (_Float16)w;
          Ah[j] = hf;
          Al[j] = (_Float16)((w - (float)hf) * 2048.0f);
        }
        #pragma unroll
        for (int nt = 0; nt < 6; ++nt) {
          const int row = nt*16 + lr;
          const uint32_t o = (uint32_t)row*256u +
              ((uint32_t)((kc*4 + lg) ^ (row & 15)) << 4);
          const f16x8 Bh = *(const f16x8*)(XH + o);
          const f16x8 Bl = *(const f16x8*)(XL + o);
          accH[nt] = __builtin_amdgcn_mfma_f32_16x16x32_f16(Ah, Bh, accH[nt], 0,0,0);
          accC[nt] = __builtin_amdgcn_mfma_f32_16x16x32_f16(Ah, Bl, accC[nt], 0,0,0);
          accC[nt] = __builtin_amdgcn_mfma_f32_16x16x32_f16(Al, Bh, accC[nt], 0,0,0);
        }
      }
      const float4 bia = *(const float4*)(in_b + rowbase + lg*4);
      #pragma unroll
      for (int nt = 0; nt < 6; ++nt) {
        const int cell = nt*16 + lr;
        float v0 = accH[nt][0] + accC[nt][0]*(1.f/2048.f) + bia.x;
        float v1 = accH[nt][1] + accC[nt][1]*(1.f/2048.f) + bia.y;
        float v2 = accH[nt][2] + accC[nt][2]*(1.f/2048.f) + bia.z;
        float v3 = accH[nt][3] + accC[nt][3]*(1.f/2048.f) + bia.w;
        if (part < 2) {
          ushort4 hw, lw;
          splitu(v0, hw.x, lw.x); splitu(v1, hw.y, lw.y);
          splitu(v2, hw.z, lw.z); splitu(v3, hw.w, lw.w);
          const int sflat = part*4 + sub*2 + (lg >> 1);   // 0..7 within hi
          const int byo   = (lg & 1)*8;
          const uint32_t adH = (uint32_t)cell*256u +
              ((uint32_t)(sflat ^ (cell & 15)) << 4) + byo;
          const uint32_t adL = (uint32_t)cell*256u +
              ((uint32_t)((8 + sflat) ^ (cell & 15)) << 4) + byo;
          *(ushort4*)(QK + adH) = hw;
          *(ushort4*)(QK + adL) = lw;
        } else {
          float vv[4] = {v0, v1, v2, v3};
          #pragma unroll
          for (int r = 0; r < 4; ++r) {
            const int hd = sub*16 + lg*4 + r;
            u16 hh, llv;
            splitu(vv[r], hh, llv);
            const uint32_t ad = (uint32_t)hd*256u +
                ((uint32_t)((cell >> 3) ^ (hd & 15)) << 4) + (cell & 7)*2;
            *(u16*)(VTH + ad) = hh;
            *(u16*)(VTL + ad) = llv;
          }
        }
      }
    }
    __syncthreads();

    // ---- scores: 36 tiles (6 qt x 6 nt) over 8 waves ----
    {
      const uint32_t mb = (h==0) ? 0xFFu : (h==1) ? 0xFF00u
                        : (h==2) ? 0xFF0000u : 0u;
      const int t0 = (wv*36) >> 3, t1 = ((wv + 1)*36) >> 3;
      for (int t = t0; t < t1; ++t) {
        const int qt = t/6, nt = t - (t/6)*6;
        const int ra = qt*16 + lr;
        const f16x8 Qh = *(const f16x8*)(QK + (uint32_t)ra*256u +
            ((uint32_t)(lg ^ (ra & 15)) << 4));
        const f16x8 Ql = *(const f16x8*)(QK + (uint32_t)ra*256u +
            ((uint32_t)((8 + lg) ^ (ra & 15)) << 4));
        const int rb = nt*16 + lr;
        const f16x8 Kh = *(const f16x8*)(QK + (uint32_t)rb*256u +
            ((uint32_t)((4 + lg) ^ (rb & 15)) << 4));
        const f16x8 Kl = *(const f16x8*)(QK + (uint32_t)rb*256u +
            ((uint32_t)((12 + lg) ^ (rb & 15)) << 4));
        f32x4 aH = (f32x4){0.f,0.f,0.f,0.f};
        f32x4 aC = (f32x4){0.f,0.f,0.f,0.f};
        aH = __builtin_amdgcn_mfma_f32_16x16x32_f16(Qh, Kh, aH, 0,0,0);
        aC = __builtin_amdgcn_mfma_f32_16x16x32_f16(Qh, Kl, aC, 0,0,0);
        aC = __builtin_amdgcn_mfma_f32_16x16x32_f16(Ql, Kh, aC, 0,0,0);
        const int kcell = nt*16 + lr;
        const uint32_t kk = RCB[kcell];
        #pragma unroll
        for (int r = 0; r < 4; ++r) {
          const int q = qt*16 + lg*4 + r;
          const uint32_t qq = RCB[q];
          const float msk = (((qq ^ kk) & mb) == 0u) ? 1.f : 0.f;
          SC[q*132 + kcell] =
              (aH[r] + aC[r]*(1.f/2048.f)) * 0.17677669529663687f + msk;
        }
      }
    }
    __syncthreads();

    // ---- softmax: 4 lanes/row, one pass, shfl reductions ----
    if (tid < 324) {
      const int row = tid >> 2, sub = tid & 3;
      float* sr = SC + row*132;
      const int kb = sub*24;
      const int ke = (sub == 3) ? 81 : kb + 24;
      float m = -1e30f;
      for (int k = kb; k < ke; ++k) m = fmaxf(m, sr[k]);
      m = fmaxf(m, __shfl_xor(m, 1));
      m = fmaxf(m, __shfl_xor(m, 2));
      float ss = 0.f;
      for (int k = kb; k < ke; ++k) {
        const float e = __expf(sr[k] - m);
        sr[k] = e;
        ss += e;
      }
      if (sub == 3) {
        #pragma unroll
        for (int k = 81; k < 96; ++k) sr[k] = 0.f;
      }
      ss += __shfl_xor(ss, 1);
      ss += __shfl_xor(ss, 2);
      if (sub == 0) RINV[row] = 1.0f / ss;
    }
    __syncthreads();

    // ---- P-pass: phase 1 read probs to regs (+asc), phase 2 write fp16 ----
    float pa[2][8];
    #pragma unroll
    for (int i = 0; i < 2; ++i) {
      const int idx = tid + i*512;
      if (idx < 972) {
        const int q = idx / 12, k8 = idx - q*12;
        const float rv = RINV[q];
        const float* sp = SC + q*132 + k8*8;
        const float4 p0 = *(const float4*)sp;
        const float4 p1 = *(const float4*)(sp + 4);
        pa[i][0] = p0.x*rv; pa[i][1] = p0.y*rv;
        pa[i][2] = p0.z*rv; pa[i][3] = p0.w*rv;
        pa[i][4] = p1.x*rv; pa[i][5] = p1.y*rv;
        pa[i][6] = p1.z*rv; pa[i][7] = p1.w*rv;
        #pragma unroll
        for (int j = 0; j < 8; ++j) ascR[i*8 + j] += pa[i][j];
      }
    }
    __syncthreads();
    #pragma unroll
    for (int i = 0; i < 2; ++i) {
      const int idx = tid + i*512;
      if (idx < 972) {
        const int q = idx / 12, k8 = idx - q*12;
        union { u16 u[8]; uint4 v; } hw, lw;
        #pragma unroll
        for (int j = 0; j < 8; ++j) splitu(pa[i][j], hw.u[j], lw.u[j]);
        const uint32_t ad = (uint32_t)q*256u +
            ((uint32_t)(k8 ^ (q & 15)) << 4);
        *(uint4*)(PH + ad) = hw.v;
        *(uint4*)(PL + ad) = lw.v;
      }
    }
    __syncthreads();

    // ---- PV: ctx[cell][hd] = V^T · P : 12 tiles (2 ot x 6 nt) ----
    for (int t = wv; t < 12; t += 8) {
      const int ot = t/6, nt = t - (t/6)*6;
      f32x4 aH = (f32x4){0.f,0.f,0.f,0.f};
      f32x4 aC = (f32x4){0.f,0.f,0.f,0.f};
      #pragma unroll
      for (int kc = 0; kc < 3; ++kc) {
        const int ra = ot*16 + lr;
        const uint32_t oa = (uint32_t)ra*256u +
            ((uint32_t)((kc*4 + lg) ^ (ra & 15)) << 4);
        const f16x8 Vh = *(const f16x8*)(VTH + oa);
        const f16x8 Vl = *(const f16x8*)(VTL + oa);
        const int rb = nt*16 + lr;
        const uint32_t ob = (uint32_t)rb*256u +
            ((uint32_t)((kc*4 + lg) ^ (rb & 15)) << 4);
        const f16x8 Pf  = *(const f16x8*)(PH + ob);
        const f16x8 Pl2 = *(const f16x8*)(PL + ob);
        aH = __builtin_amdgcn_mfma_f32_16x16x32_f16(Vh, Pf,  aH, 0,0,0);
        aC = __builtin_amdgcn_mfma_f32_16x16x32_f16(Vh, Pl2, aC, 0,0,0);
        aC = __builtin_amdgcn_mfma_f32_16x16x32_f16(Vl, Pf,  aC, 0,0,0);
      }
      const int cell = nt*16 + lr;
      if (cell < 81) {
        const size_t co = ((size_t)b*81 + cell)*128 + h*32 + ot*16 + lg*4;
        ushort4 hw, lw;
        float r0 = aH[0] + aC[0]*(1.f/2048.f);
        float r1 = aH[1] + aC[1]*(1.f/2048.f);
        float r2 = aH[2] + aC[2]*(1.f/2048.f);
        float r3 = aH[3] + aC[3]*(1.f/2048.f);
        splitu(r0, hw.x, lw.x); splitu(r1, hw.y, lw.y);
        splitu(r2, hw.z, lw.z); splitu(r3, hw.w, lw.w);
        *(ushort4*)(ctxh + co) = hw;
        *(ushort4*)(ctxl + co) = lw;
      }
    }
    __syncthreads();
  } // heads

  // asc = mean over heads
  #pragma unroll
  for (int i = 0; i < 2; ++i) {
    const int idx = tid + i*512;
    if (idx < 972) {
      const int q = idx / 12, k8 = idx - q*12;
      #pragma unroll
      for (int j = 0; j < 8; ++j) {
        const int k = k8*8 + j;
        if (k < 81) asc[(size_t)b*6561 + q*81 + k] = 0.25f * ascR[i*8 + j];
      }
    }
  }
}

// ---------------- post (MFMA): out-proj -> LN -> l1 -> l2 -> heads ---------
// 512 threads (8 waves). Wave wv owns otile wv (oc 16wv..16wv+15), 6 ntiles.
// LDS: YH/YL, ZH/ZL [96 rows][256B] fp16 hi/lo, slot ^= (row&15).
//  YH 0 | YL 24576 | ZH 49152 | ZL 73728 | red1 98304 (96*8 f) |
//  red2 101376 | mu 104448 | rstd 104832 | vals 105216 | posIdx 105600
#define POST_LDS_BYTES 105664

__global__ __launch_bounds__(512, 1) void k_post(
    const u16* __restrict__ ctxh, const u16* __restrict__ ctxl,
    const u16* __restrict__ WOh,  const float* __restrict__ out_b,
    const float* __restrict__ ln_g, const float* __restrict__ ln_b,
    const u16* __restrict__ W1h,  const float* __restrict__ l1_b,
    const u16* __restrict__ W2h,  const float* __restrict__ l2_b,
    const float* __restrict__ pos_w, const float* __restrict__ pos_b,
    const float* __restrict__ num_w, const float* __restrict__ num_b,
    const int* __restrict__ digits,  float* __restrict__ dout)
{
  extern __shared__ char smc[];
  char*  YH   = smc;
  char*  YL   = smc + 24576;
  char*  ZH   = smc + 49152;
  char*  ZL   = smc + 73728;
  float* red1 = (float*)(smc + 98304);
  float* red2 = (float*)(smc + 101376);
  float* mu   = (float*)(smc + 104448);
  float* rstd = (float*)(smc + 104832);
  float* vals = (float*)(smc + 105216);
  int*   posi = (int*)(smc + 105600);

  const int b   = blockIdx.x;
  const int tid = threadIdx.x;
  const int ln  = tid & 63;
  const int wv  = tid >> 6;
  const int lg  = ln >> 4;
  const int lr  = ln & 15;
  const int ocb = wv*16 + lg*4;     // this lane's 4 output channels

  // ---- stage ctx -> YH/YL, zero pad rows ----
  {
    const u16* gh = ctxh + (size_t)b*81*128;
    const u16* gl = ctxl + (size_t)b*81*128;
    for (int i = tid; i < 1296; i += 512) {
      const int n = i >> 4, k8 = i & 15;
      const uint4 hv = *(const uint4*)(gh + n*128 + k8*8);
      const uint4 lv = *(const uint4*)(gl + n*128 + k8*8);
      const uint32_t bo = (uint32_t)n*256u + ((uint32_t)(k8 ^ (n & 15)) << 4);
      *(uint4*)(YH + bo) = hv;
      *(uint4*)(YL + bo) = lv;
    }
    for (int i = tid; i < 480; i += 512) {
      char* base = (i < 240) ? YH : YL;
      const int j = (i < 240) ? i : (i - 240);
      *(uint4*)(base + 81*256 + j*16) = make_uint4(0u,0u,0u,0u);
    }
  }
  __syncthreads();

  // GEMM over this wave's otile: D[oc][cell] for 6 ntiles
  f32x4 aH[6], aC[6];
  #define GEMM6(BH, BL, WT)                                               \
    {                                                                     \
      _Pragma("unroll")                                                   \
      for (int nt = 0; nt < 6; ++nt) {                                    \
        aH[nt] = (f32x4){0.f,0.f,0.f,0.f};                                \
        aC[nt] = (f32x4){0.f,0.f,0.f,0.f};                                \
      }                                                                   \
      for (int kc = 0; kc < 4; ++kc) {                                    \
        const int ab = ((kc*8 + wv)*64 + ln)*8;                           \
        const f16x8 Ah = *(const f16x8*)((WT) + ab);                      \
        const f16x8 Al = *(const f16x8*)((WT) + 16384 + ab);              \
        _Pragma("unroll")                                                 \
        for (int nt = 0; nt < 6; ++nt) {                                  \
          const int row = nt*16 + lr;                                     \
          const uint32_t o = (uint32_t)row*256u +                         \
              ((uint32_t)((kc*4 + lg) ^ (row & 15)) << 4);                \
          const f16x8 Bh = *(const f16x8*)((BH) + o);                     \
          const f16x8 Bl = *(const f16x8*)((BL) + o);                     \
          aH[nt] = __builtin_amdgcn_mfma_f32_16x16x32_f16(Ah, Bh, aH[nt], 0,0,0); \
          aC[nt] = __builtin_amdgcn_mfma_f32_16x16x32_f16(Ah, Bl, aC[nt], 0,0,0); \
          aC[nt] = __builtin_amdgcn_mfma_f32_16x16x32_f16(Al, Bh, aC[nt], 0,0,0); \
        }                                                                 \
      }                                                                   \
    }

  // ---- out projection ----
  GEMM6(YH, YL, WOh);
  float y[6][4];
  {
    const float4 bv = *(const float4*)(out_b + ocb);
    #pragma unroll
    for (int nt = 0; nt < 6; ++nt) {
      y[nt][0] = aH[nt][0] + aC[nt][0]*(1.f/2048.f) + bv.x;
      y[nt][1] = aH[nt][1] + aC[nt][1]*(1.f/2048.f) + bv.y;
      y[nt][2] = aH[nt][2] + aC[nt][2]*(1.f/2048.f) + bv.z;
      y[nt][3] = aH[nt][3] + aC[nt][3]*(1.f/2048.f) + bv.w;
    }
  }

  // ---- LayerNorm over oc, two-pass ----
  #pragma unroll
  for (int nt = 0; nt < 6; ++nt) {
    float s1 = y[nt][0] + y[nt][1] + y[nt][2] + y[nt][3];
    s1 += __shfl_xor(s1, 16);
    s1 += __shfl_xor(s1, 32);
    if (ln < 16) red1[(nt*16 + lr)*8 + wv] = s1;
  }
  __syncthreads();
  if (tid < 96) {
    float s = 0.f;
    #pragma unroll
    for (int w = 0; w < 8; ++w) s += red1[tid*8 + w];
    mu[tid] = s * (1.0f/128.0f);
  }
  __syncthreads();
  #pragma unroll
  for (int nt = 0; nt < 6; ++nt) {
    const float m = mu[nt*16 + lr];
    float d0 = y[nt][0]-m, d1 = y[nt][1]-m, d2 = y[nt][2]-m, d3 = y[nt][3]-m;
    float s2 = d0*d0 + d1*d1 + d2*d2 + d3*d3;
    s2 += __shfl_xor(s2, 16);
    s2 += __shfl_xor(s2, 32);
    if (ln < 16) red2[(nt*16 + lr)*8 + wv] = s2;
  }
  __syncthreads();
  if (tid < 96) {
    float s = 0.f;
    #pragma unroll
    for (int w = 0; w < 8; ++w) s += red2[tid*8 + w];
    rstd[tid] = 1.0f / sqrtf(s * (1.0f/128.0f) + 1e-5f);
  }
  __syncthreads();
  {
    const float4 g  = *(const float4*)(ln_g + ocb);
    const float4 bb = *(const float4*)(ln_b + ocb);
    #pragma unroll
    for (int nt = 0; nt < 6; ++nt) {
      const int cell = nt*16 + lr;
      const float m = mu[cell], rs = rstd[cell];
      float z0 = (y[nt][0]-m)*rs*g.x + bb.x;
      float z1 = (y[nt][1]-m)*rs*g.y + bb.y;
      float z2 = (y[nt][2]-m)*rs*g.z + bb.z;
      float z3 = (y[nt][3]-m)*rs*g.w + bb.w;
      ushort4 hw, lw;
      splitu(z0, hw.x, lw.x); splitu(z1, hw.y, lw.y);
      splitu(z2, hw.z, lw.z); splitu(z3, hw.w, lw.w);
      const uint32_t ad = (uint32_t)cell*256u +
          ((uint32_t)((wv*2 + (lg >> 1)) ^ (cell & 15)) << 4) + (lg & 1)*8;
      *(ushort4*)(ZH + ad) = hw;
      *(ushort4*)(ZL + ad) = lw;
    }
  }
  __syncthreads();

  // ---- l1 (silu): reads ZH/ZL, writes YH/YL ----
  GEMM6(ZH, ZL, W1h);
  {
    const float4 bv = *(const float4*)(l1_b + ocb);
    #pragma unroll
    for (int nt = 0; nt < 6; ++nt) {
      const int cell = nt*16 + lr;
      float z0 = silu_f(aH[nt][0] + aC[nt][0]*(1.f/2048.f) + bv.x);
      float z1 = silu_f(aH[nt][1] + aC[nt][1]*(1.f/2048.f) + bv.y);
      float z2 = silu_f(aH[nt][2] + aC[nt][2]*(1.f/2048.f) + bv.z);
      float z3 = silu_f(aH[nt][3] + aC[nt][3]*(1.f/2048.f) + bv.w);
      ushort4 hw, lw;
      splitu(z0, hw.x, lw.x); splitu(z1, hw.y, lw.y);
      splitu(z2, hw.z, lw.z); splitu(z3, hw.w, lw.w);
      const uint32_t ad = (uint32_t)cell*256u +
          ((uint32_t)((wv*2 + (lg >> 1)) ^ (cell & 15)) << 4) + (lg & 1)*8;
      *(ushort4*)(YH + ad) = hw;
      *(ushort4*)(YL + ad) = lw;
    }
  }
  __syncthreads();

  // ---- l2 (silu): reads YH/YL, writes ZH/ZL; pos partials fused ----
  GEMM6(YH, YL, W2h);
  {
    const float4 bv = *(const float4*)(l2_b + ocb);
    const float4 pw = *(const float4*)(pos_w + ocb);
    #pragma unroll
    for (int nt = 0; nt < 6; ++nt) {
      const int cell = nt*16 + lr;
      float z0 = silu_f(aH[nt][0] + aC[nt][0]*(1.f/2048.f) + bv.x);
      float z1 = silu_f(aH[nt][1] + aC[nt][1]*(1.f/2048.f) + bv.y);
      float z2 = silu_f(aH[nt][2] + aC[nt][2]*(1.f/2048.f) + bv.z);
      float z3 = silu_f(aH[nt][3] + aC[nt][3]*(1.f/2048.f) + bv.w);
      ushort4 hw, lw;
      splitu(z0, hw.x, lw.x); splitu(z1, hw.y, lw.y);
      splitu(z2, hw.z, lw.z); splitu(z3, hw.w, lw.w);
      const uint32_t ad = (uint32_t)cell*256u +
          ((uint32_t)((wv*2 + (lg >> 1)) ^ (cell & 15)) << 4) + (lg & 1)*8;
      *(ushort4*)(ZH + ad) = hw;
      *(ushort4*)(ZL + ad) = lw;
      float ps = z0*pw.x + z1*pw.y + z2*pw.z + z3*pw.w;
      ps += __shfl_xor(ps, 16);
      ps += __shfl_xor(ps, 32);
      if (ln < 16) red1[cell*8 + wv] = ps;
    }
  }
  __syncthreads();

  // ---- position head + gumbel sampling ----
  uint32_t k1a, k1b, k2a, k2b;
  jax_split42(k1a, k1b, k2a, k2b);

  if (tid < 81) {
    float acc = pos_b[0];
    #pragma unroll
    for (int w = 0; w < 8; ++w) acc += red1[tid*8 + w];
    if (digits[b*81 + tid] != 0) acc = -1e9f;
    uint32_t bits = jax_randbits(k1a, k1b, (uint32_t)(b*81 + tid));
    vals[tid] = acc + jax_gumbel_bits(bits);
  }
  __syncthreads();
  if (tid == 0) {
    float best = vals[0]; int bi = 0;
    for (int n = 1; n < 81; ++n)
      if (vals[n] > best) { best = vals[n]; bi = n; }
    *posi = bi;
    dout[b] = (float)bi;
  }
  __syncthreads();
  const int pos = *posi;

  // ---- number head at sampled position ----
  if (tid < 80) {
    const int d = tid >> 3, j = tid & 7;
    float ssum = 0.f;
    #pragma unroll
    for (int c = 0; c < 16; ++c) {
      const int k = j*16 + c;
      const uint32_t ad = (uint32_t)pos*256u +
          ((uint32_t)((k >> 3) ^ (pos & 15)) << 4) + (k & 7)*2;
      const float yv = joinu(*(const u16*)(ZH + ad), *(const u16*)(ZL + ad));
      ssum += yv * num_w[d*128 + k];
    }
    red2[tid] = ssum;
  }
  __syncthreads();
  if (tid < 10) {
    float acc = num_b[tid];
    #pragma unroll
    for (int j = 0; j < 8; ++j) acc += red2[tid*8 + j];
    if (tid == 0) acc = -INFINITY;
    uint32_t bits = jax_randbits(k2a, k2b, (uint32_t)(b*10 + tid));
    vals[tid] = acc + jax_gumbel_bits(bits);
  }
  __syncthreads();
  if (tid == 0) {
    float best = vals[0]; int bi = 0;
    for (int d = 1; d < 10; ++d)
      if (vals[d] > best) { best = vals[d]; bi = d; }
    dout[NB + b] = (float)bi;
  }
}

// ---------------------------------------------------------------------------
extern "C" void kernel_launch(void* const* d_in, const int* in_sizes, int n_in,
                              void* d_out, int out_size, void* d_ws, size_t ws_size,
                              hipStream_t stream) {
  const float* s     = (const float*)d_in[0];
  const float* c1_w  = (const float*)d_in[1];
  const float* c1_b  = (const float*)d_in[2];
  const float* c2_w  = (const float*)d_in[3];
  const float* c2_b  = (const float*)d_in[4];
  const float* c3_w  = (const float*)d_in[5];
  const float* c3_b  = (const float*)d_in[6];
  const float* emb   = (const float*)d_in[7];
  const float* in_w  = (const float*)d_in[8];
  const float* in_b  = (const float*)d_in[9];
  const float* out_w = (const float*)d_in[10];
  const float* out_b = (const float*)d_in[11];
  const float* ln_g  = (const float*)d_in[12];
  const float* ln_b  = (const float*)d_in[13];
  const float* l1_w  = (const float*)d_in[14];
  const float* l1_b  = (const float*)d_in[15];
  const float* l2_w  = (const float*)d_in[16];
  const float* l2_b  = (const float*)d_in[17];
  const float* pos_w = (const float*)d_in[18];
  const float* pos_b = (const float*)d_in[19];
  const float* num_w = (const float*)d_in[20];
  const float* num_b = (const float*)d_in[21];

  // ws layout (floats):
  // T2e 0 (12672) | WAh 12672 (73728 f as u16) | WAl 86400 | WOh/WOl 160128
  // (16384 f = 32768 u16) | W1 176512 | W2 192896 | digits 209280 |
  // xh 541056 (u16) | xl 21774720 (u16) | ctxh 43008384 (u16) | ctxl +half
  float* ws     = (float*)d_ws;
  float* T2e    = ws;
  u16*   WAh    = (u16*)(ws + 12672);
  u16*   WAl    = (u16*)(ws + 86400);
  u16*   WOh    = (u16*)(ws + 160128);
  u16*   W1h    = (u16*)(ws + 176512);
  u16*   W2h    = (u16*)(ws + 192896);
  int*   digits = (int*)(ws + 209280);
  u16*   xh     = (u16*)(ws + 541056);
  u16*   xl     = (u16*)(ws + 21774720);
  u16*   ctxh   = (u16*)(ws + 43008384);
  u16*   ctxl   = (u16*)(ws + 43008384 + 21233664);

  float* dout = (float*)d_out;
  float* asc  = dout + 2*NB;

  hipFuncSetAttribute((const void*)k_attn,
                      hipFuncAttributeMaxDynamicSharedMemorySize,
                      ATTN_LDS_BYTES);
  hipFuncSetAttribute((const void*)k_post,
                      hipFuncAttributeMaxDynamicSharedMemorySize,
                      POST_LDS_BYTES);

  k_prep<<<dim3(818), dim3(256), 0, stream>>>(
      c1_w, c1_b, c2_w, c3_w, out_w, l1_w, l2_w,
      T2e, WAh, WAl, WOh, W1h, W2h);
  k_stem<<<dim3(NB), dim3(256), 0, stream>>>(
      s, T2e, c2_b, WAh, WAl, c3_b, emb, xh, xl, digits);
  k_attn<<<dim3(NB), dim3(512), ATTN_LDS_BYTES, stream>>>(
      xh, xl, in_w, in_b, ctxh, ctxl, asc);
  k_post<<<dim3(NB), dim3(512), POST_LDS_BYTES, stream>>>(
      ctxh, ctxl, WOh, out_b, ln_g, ln_b, W1h, l1_b, W2h, l2_b,
      pos_w, pos_b, num_w, num_b, digits, dout);
}

// Round 7
// 1421.221 us; speedup vs baseline: 1.4418x; 1.0133x over previous
//
#include <hip/hip_runtime.h>
#include <stdint.h>
#include <math.h>

// ---------------------------------------------------------------------------
// p_net forward on MI355X.  B=4096 boards, N=81 cells, D=128, H=4 heads.
// Round 13 (= round 12 resubmitted after infra failure): k_attn phase surgery.
//  - in_w pre-packed as MFMA fragments hi/lo (WIh/WIl) in k_prep: QKV does
//    zero weight conversion (8 L2-hot 16B loads/unit instead).
//  - QKV spread over all 8 waves as 36 (otile,ntile) units sorted by ntile
//    with B-fragment register caching (round-2 shape, conversion cost now 0).
//  - softmax+P merged: e kept in regs (float4 SC reads), shfl max/sum, one
//    barrier, direct normalized P hi/lo chunk writes + asc fold. RINV gone,
//    SC pad-zeroing gone, one less barrier + one less LDS round trip/head.
// k_stem, k_post unchanged from round 11.
// Outputs (concat, float32): pos[4096], num[4096], asc[4096*81*81].
// ---------------------------------------------------------------------------

#define NB 4096

typedef unsigned short u16;
typedef _Float16 f16x8 __attribute__((ext_vector_type(8)));
typedef float f32x4 __attribute__((ext_vector_type(4)));

__device__ __forceinline__ float silu_f(float v) {
  return v / (1.0f + expf(-v));
}

// split fp32 -> fp16 hi + fp16 lo (lo scaled by 2^11 to dodge denormals)
__device__ __forceinline__ void splitu(float v, u16& h, u16& l) {
  _Float16 hf = (_Float16)v;
  _Float16 lf = (_Float16)((v - (float)hf) * 2048.0f);
  union { _Float16 f; u16 u; } a, b;
  a.f = hf; b.f = lf;
  h = a.u; l = b.u;
}

__device__ __forceinline__ float joinu(u16 h, u16 l) {
  union { u16 u; _Float16 f; } a, b;
  a.u = h; b.u = l;
  return (float)a.f + (float)b.f * (1.f/2048.f);
}

// ---------------- Threefry-2x32 (JAX partitionable) ------------------------
__device__ __forceinline__ void tf_round(uint32_t& x0, uint32_t& x1, int r) {
  x0 += x1;
  x1 = (x1 << r) | (x1 >> (32 - r));
  x1 ^= x0;
}

__device__ __forceinline__ void threefry2x32(uint32_t k0, uint32_t k1,
                                             uint32_t x0, uint32_t x1,
                                             uint32_t& o0, uint32_t& o1) {
  uint32_t k2 = k0 ^ k1 ^ 0x1BD11BDAu;
  x0 += k0; x1 += k1;
  tf_round(x0,x1,13); tf_round(x0,x1,15); tf_round(x0,x1,26); tf_round(x0,x1,6);
  x0 += k1; x1 += k2 + 1u;
  tf_round(x0,x1,17); tf_round(x0,x1,29); tf_round(x0,x1,16); tf_round(x0,x1,24);
  x0 += k2; x1 += k0 + 2u;
  tf_round(x0,x1,13); tf_round(x0,x1,15); tf_round(x0,x1,26); tf_round(x0,x1,6);
  x0 += k0; x1 += k1 + 3u;
  tf_round(x0,x1,17); tf_round(x0,x1,29); tf_round(x0,x1,16); tf_round(x0,x1,24);
  x0 += k1; x1 += k2 + 4u;
  tf_round(x0,x1,13); tf_round(x0,x1,15); tf_round(x0,x1,26); tf_round(x0,x1,6);
  x0 += k2; x1 += k0 + 5u;
  o0 = x0; o1 = x1;
}

__device__ __forceinline__ void jax_split42(uint32_t& k1a, uint32_t& k1b,
                                            uint32_t& k2a, uint32_t& k2b) {
  threefry2x32(0u, 42u, 0u, 0u, k1a, k1b);
  threefry2x32(0u, 42u, 0u, 1u, k2a, k2b);
}

__device__ __forceinline__ uint32_t jax_randbits(uint32_t ka, uint32_t kb,
                                                 uint32_t i) {
  uint32_t o0, o1;
  threefry2x32(ka, kb, 0u, i, o0, o1);
  return o0 ^ o1;
}

__device__ __forceinline__ float jax_gumbel_bits(uint32_t bits) {
  float f = __uint_as_float((bits >> 9) | 0x3f800000u) - 1.0f;
  const float tiny = 1.17549435e-38f;
  float u = fmaxf(tiny, f + tiny);
  return -logf(-logf(u));
}

// ---------------- prep: conv tables + fragment-packed weights --------------
// WAh/WAl (conv3): [(d*4+kc)*8 + ot][lane][j].
// WO/W1/W2: [(kc*8+ot)][lane][j], lo at +16384 u16.
// WIh/WIl (in_w): [((h*6+pu)*4+kc)][lane][j], pu = part*2+sub.
// Fragment semantics: m = lane&15 (oc), k = kc*32 + (lane>>4)*8 + j.
__global__ __launch_bounds__(256) void k_prep(
    const float* __restrict__ c1_w, const float* __restrict__ c1_b,
    const float* __restrict__ c2_w, const float* __restrict__ c3_w,
    const float* __restrict__ in_w,
    const float* __restrict__ out_w, const float* __restrict__ l1_w,
    const float* __restrict__ l2_w,
    float* __restrict__ T2e, u16* __restrict__ WAh, u16* __restrict__ WAl,
    u16* __restrict__ WIh, u16* __restrict__ WIl,
    u16* __restrict__ WOh, u16* __restrict__ W1h, u16* __restrict__ W2h)
{
  int idx = blockIdx.x * 256 + threadIdx.x;
  if (idx < 9*11*128) {
    int oc = idx & 127;
    int t  = idx >> 7;
    int g  = t % 11;
    int d  = t / 11;
    float acc = 0.f;
    if (g < 10) {
      int di = d / 3, dj = d % 3;
      for (int ic = 0; ic < 64; ++ic) {
        float x1 = c1_w[ic*10 + g] + c1_b[ic];
        acc += c2_w[((oc*64 + ic)*3 + di)*3 + dj] * x1;
      }
    }
    T2e[idx] = acc;
  } else if (idx < 160128) {
    int j  = idx - 12672;          // 0..147455
    int jj = j & 7;
    int t  = j >> 3;               // ((d*4+kc)*8+ot)*64 + lane
    int ln = t & 63;
    int t2 = t >> 6;               // (d*4+kc)*8 + ot
    int ot = t2 & 7;
    int t3 = t2 >> 3;              // d*4 + kc
    int kc = t3 & 3;
    int d  = t3 >> 2;
    int oc = ot*16 + (ln & 15);
    int ic = kc*32 + (ln >> 4)*8 + jj;
    float w = c3_w[(oc*128 + ic)*9 + d];
    u16 wh, wl;
    splitu(w, wh, wl);
    WAh[j] = wh; WAl[j] = wl;
  } else if (idx < 209280) {
    int j = idx - 160128;          // 0..49151 over 3 matrices
    int mi = j >> 14;              // 0..2
    int jr = j & 16383;
    int jj = jr & 7;
    int t  = jr >> 3;
    int ln = t & 63;
    int t2 = t >> 6;               // kc*8 + ot
    int ot = t2 & 7;
    int kc = t2 >> 3;
    int oc = ot*16 + (ln & 15);
    int k  = kc*32 + (ln >> 4)*8 + jj;
    const float* W = (mi == 0) ? out_w : (mi == 1) ? l1_w : l2_w;
    u16* Dh = (mi == 0) ? WOh : (mi == 1) ? W1h : W2h;
    u16 wh, wl;
    splitu(W[oc*128 + k], wh, wl);
    Dh[jr] = wh; Dh[16384 + jr] = wl;
  } else if (idx < 258432) {
    int j  = idx - 209280;         // 0..49151
    int jj = j & 7;
    int t  = j >> 3;               // 0..6143
    int ln = t & 63;
    int t2 = t >> 6;               // (h*6+pu)*4 + kc
    int kc = t2 & 3;
    int t3 = t2 >> 2;              // h*6 + pu
    int h  = t3 / 6;
    int pu = t3 - h*6;
    int part = pu >> 1, sub = pu & 1;
    int row = part*128 + h*32 + sub*16 + (ln & 15);
    int k   = kc*32 + (ln >> 4)*8 + jj;
    u16 wh, wl;
    splitu(in_w[row*128 + k], wh, wl);
    WIh[j] = wh; WIl[j] = wl;
  }
}

// ---------------- stem: digits -> conv2(table, fp16 hi/lo in LDS)
//                  -> conv3 on MFMA (split-fp16) -> +emb, write x hi/lo ----
__global__ __launch_bounds__(256, 2) void k_stem(
    const float* __restrict__ s, const float* __restrict__ T2e,
    const float* __restrict__ c2_b,
    const u16* __restrict__ WAh, const u16* __restrict__ WAl,
    const float* __restrict__ c3_b, const float* __restrict__ emb,
    u16* __restrict__ xh, u16* __restrict__ xl, int* __restrict__ digits)
{
  __shared__ __align__(16) u16 x2h[121*128];   // 30976 B
  __shared__ __align__(16) u16 x2l[121*128];   // 30976 B
  __shared__ int dg[121];                      // padded digit grid, 10 = pad
  const int b   = blockIdx.x;
  const int tid = threadIdx.x;

  for (int i = tid; i < 1936; i += 256) {
    ((uint4*)x2h)[i] = make_uint4(0u,0u,0u,0u);
    ((uint4*)x2l)[i] = make_uint4(0u,0u,0u,0u);
  }
  if (tid < 121) dg[tid] = 10;
  __syncthreads();

  if (tid < 81) {
    const float* sp = s + (size_t)b*810 + tid;
    float dv = 0.f;
    #pragma unroll
    for (int c = 1; c < 10; ++c) dv += (float)c * sp[c*81];
    int d = (int)(dv + 0.5f);
    dg[(tid/9 + 1)*11 + (tid%9 + 1)] = d;
    digits[b*81 + tid] = d;
  }
  __syncthreads();

  // ---- conv2 via table: 81 cells x 16 chunks of 8 channels ----
  for (int i = tid; i < 1296; i += 256) {
    const int p  = i >> 4;
    const int k8 = i & 15;
    const int r0 = p / 9, c0 = p - r0*9;
    const float4 b0 = *(const float4*)(c2_b + k8*8);
    const float4 b1 = *(const float4*)(c2_b + k8*8 + 4);
    float a0=b0.x, a1=b0.y, a2=b0.z, a3=b0.w;
    float a4=b1.x, a5=b1.y, a6=b1.z, a7=b1.w;
    #pragma unroll
    for (int d = 0; d < 9; ++d) {
      const int g = dg[(r0 + d/3)*11 + (c0 + d%3)];
      const float* tp = T2e + (size_t)(d*11 + g)*128 + k8*8;
      const float4 t0 = *(const float4*)tp;
      const float4 t1 = *(const float4*)(tp + 4);
      a0 += t0.x; a1 += t0.y; a2 += t0.z; a3 += t0.w;
      a4 += t1.x; a5 += t1.y; a6 += t1.z; a7 += t1.w;
    }
    float v[8];
    v[0]=silu_f(a0); v[1]=silu_f(a1); v[2]=silu_f(a2); v[3]=silu_f(a3);
    v[4]=silu_f(a4); v[5]=silu_f(a5); v[6]=silu_f(a6); v[7]=silu_f(a7);
    f16x8 hv, lv;
    #pragma unroll
    for (int j = 0; j < 8; ++j) {
      _Float16 h = (_Float16)v[j];
      hv[j] = h;
      lv[j] = (_Float16)((v[j] - (float)h) * 2048.0f);
    }
    const int row = (r0 + 1)*11 + (c0 + 1);
    const uint32_t bo = (uint32_t)row*256u + ((uint32_t)(k8 ^ (row & 15)) << 4);
    *(f16x8*)((char*)x2h + bo) = hv;
    *(f16x8*)((char*)x2l + bo) = lv;
  }
  __syncthreads();

  // ---- conv3 on MFMA ----
  const int ln  = tid & 63;
  const int wv  = tid >> 6;
  const int lg  = ln >> 4;
  const int lr  = ln & 15;
  const int otB = (wv & 1) * 4;
  const int ntB = (wv >> 1) * 3;

  f32x4 accH[4][3];
  f32x4 accC[4][3];
  #pragma unroll
  for (int ot = 0; ot < 4; ++ot)
    #pragma unroll
    for (int nt = 0; nt < 3; ++nt) {
      accH[ot][nt] = (f32x4){0.f,0.f,0.f,0.f};
      accC[ot][nt] = (f32x4){0.f,0.f,0.f,0.f};
    }

  int pbase[3];
  #pragma unroll
  for (int nt = 0; nt < 3; ++nt) {
    const int c = (ntB + nt)*16 + lr;
    pbase[nt] = (c < 81) ? (c/9)*11 + (c%9) : 0;
  }
  const char* x2hB = (const char*)x2h;
  const char* x2lB = (const char*)x2l;

  for (int d = 0; d < 9; ++d) {
    const int off = (d/3)*11 + (d - (d/3)*3);
    int rowv[3];
    #pragma unroll
    for (int nt = 0; nt < 3; ++nt) rowv[nt] = pbase[nt] + off;
    #pragma unroll
    for (int kc = 0; kc < 4; ++kc) {
      f16x8 Bh[3], Bl[3];
      #pragma unroll
      for (int nt = 0; nt < 3; ++nt) {
        const uint32_t o = (uint32_t)rowv[nt]*256u +
            ((uint32_t)((kc*4 + lg) ^ (rowv[nt] & 15)) << 4);
        Bh[nt] = *(const f16x8*)(x2hB + o);
        Bl[nt] = *(const f16x8*)(x2lB + o);
      }
      const int abase = (((d*4 + kc)*8 + otB)*64 + ln)*8;
      f16x8 Ah[4], Al[4];
      #pragma unroll
      for (int ot = 0; ot < 4; ++ot) {
        Ah[ot] = *(const f16x8*)(WAh + abase + ot*512);
        Al[ot] = *(const f16x8*)(WAl + abase + ot*512);
      }
      #pragma unroll
      for (int ot = 0; ot < 4; ++ot)
        #pragma unroll
        for (int nt = 0; nt < 3; ++nt) {
          accH[ot][nt] = __builtin_amdgcn_mfma_f32_16x16x32_f16(
              Ah[ot], Bh[nt], accH[ot][nt], 0, 0, 0);
          accC[ot][nt] = __builtin_amdgcn_mfma_f32_16x16x32_f16(
              Ah[ot], Bl[nt], accC[ot][nt], 0, 0, 0);
          accC[ot][nt] = __builtin_amdgcn_mfma_f32_16x16x32_f16(
              Al[ot], Bh[nt], accC[ot][nt], 0, 0, 0);
        }
    }
  }

  // ---- epilogue: y = silu(hh + corr*2^-11 + bias) + emb -> xh/xl hi/lo ----
  #pragma unroll
  for (int nt = 0; nt < 3; ++nt) {
    const int cell = (ntB + nt)*16 + lr;
    if (cell < 81) {
      const size_t xoff = ((size_t)b*81 + cell)*128;
      #pragma unroll
      for (int ot = 0; ot < 4; ++ot) {
        const int oc = (otB + ot)*16 + lg*4;
        const float4 b3 = *(const float4*)(c3_b + oc);
        const float4 e  = *(const float4*)(emb + cell*128 + oc);
        const f32x4 hh = accH[ot][nt];
        const f32x4 cc = accC[ot][nt];
        float o0 = silu_f(hh[0] + cc[0]*(1.f/2048.f) + b3.x) + e.x;
        float o1 = silu_f(hh[1] + cc[1]*(1.f/2048.f) + b3.y) + e.y;
        float o2 = silu_f(hh[2] + cc[2]*(1.f/2048.f) + b3.z) + e.z;
        float o3 = silu_f(hh[3] + cc[3]*(1.f/2048.f) + b3.w) + e.w;
        ushort4 hv, lv;
        splitu(o0, hv.x, lv.x); splitu(o1, hv.y, lv.y);
        splitu(o2, hv.z, lv.z); splitu(o3, hv.w, lv.w);
        *(ushort4*)(xh + xoff + oc) = hv;
        *(ushort4*)(xl + xoff + oc) = lv;
      }
    }
  }
}

// ---------------- attention (MFMA, split-fp16, lean phases) ----------------
// 512 threads (8 waves) / board. LDS byte layout:
//  XH/XL @ 0 / 24576   [96 cells][256B] fp16, slot ^= (row&15)
//  QK    @ 49152       [96 cells][256B] merged hi slots 0-7, lo 8-15
//  VTH/VTL @ 73728 / 81920  [32 hd][256B], slot ^= (hd&15)
//  SC    @ 90112       [96][132] f32 scores; aliased by PH/PL fp16 probs
//  RCB   @ 141184      [96] u32 packed row|col<<8|box<<16
#define ATTN_LDS_BYTES 141568

__global__ __launch_bounds__(512, 1) void k_attn(
    const u16* __restrict__ xhg, const u16* __restrict__ xlg,
    const u16* __restrict__ WIh, const u16* __restrict__ WIl,
    const float* __restrict__ in_b,
    u16* __restrict__ ctxh, u16* __restrict__ ctxl, float* __restrict__ asc)
{
  extern __shared__ char smc[];
  char*  XH   = smc;
  char*  XL   = smc + 24576;
  char*  QK   = smc + 49152;
  char*  VTH  = smc + 73728;
  char*  VTL  = smc + 81920;
  float* SC   = (float*)(smc + 90112);
  char*  PH   = smc + 90112;
  char*  PL   = smc + 114688;
  uint32_t* RCB = (uint32_t*)(smc + 141184);

  const int b   = blockIdx.x;
  const int tid = threadIdx.x;
  const int ln  = tid & 63;
  const int wv  = tid >> 6;
  const int lg  = ln >> 4;
  const int lr  = ln & 15;

  if (tid < 96) {
    const int r = tid/9, c = tid - r*9;
    const int bx = (r/3)*3 + c/3;
    RCB[tid] = (uint32_t)r | ((uint32_t)c << 8) | ((uint32_t)bx << 16);
  }
  // stage x rows 0-80 (direct 16B copies), zero pad rows 81-95
  {
    const u16* gx = xhg + (size_t)b*81*128;
    const u16* gl = xlg + (size_t)b*81*128;
    for (int i = tid; i < 1296; i += 512) {
      const int n = i >> 4, k8 = i & 15;
      const uint4 hv = *(const uint4*)(gx + n*128 + k8*8);
      const uint4 lv = *(const uint4*)(gl + n*128 + k8*8);
      const uint32_t bo = (uint32_t)n*256u + ((uint32_t)(k8 ^ (n & 15)) << 4);
      *(uint4*)(XH + bo) = hv;
      *(uint4*)(XL + bo) = lv;
    }
    for (int i = tid; i < 480; i += 512) {
      char* base = (i < 240) ? XH : XL;
      const int j = (i < 240) ? i : (i - 240);
      *(uint4*)(base + 81*256 + j*16) = make_uint4(0u,0u,0u,0u);
    }
  }

  // softmax-thread ownership: thread (row = tid>>2, sub = tid&3) owns
  // k-range [sub*24, sub*24+24) of its row; ascR accumulates over heads.
  const int srow = tid >> 2;
  const int ssub = tid & 3;
  const int skn  = (ssub == 3) ? 9 : 24;   // valid k count (k<81)
  float ascR[24];
  #pragma unroll
  for (int i = 0; i < 24; ++i) ascR[i] = 0.f;

  __syncthreads();

  for (int h = 0; h < 4; ++h) {
    // ---- QKV: 36 units (u = nt*6 + pu), spread over all 8 waves ----
    {
      const int t0 = (wv*36) >> 3, t1 = ((wv + 1)*36) >> 3;
      int curNt = -1;
      f16x8 Bh[4], Bl[4];
      for (int u = t0; u < t1; ++u) {
        const int nt = u/6, pu = u - (u/6)*6;
        if (nt != curNt) {
          curNt = nt;
          const int row = nt*16 + lr;
          #pragma unroll
          for (int kc = 0; kc < 4; ++kc) {
            const uint32_t o = (uint32_t)row*256u +
                ((uint32_t)((kc*4 + lg) ^ (row & 15)) << 4);
            Bh[kc] = *(const f16x8*)(XH + o);
            Bl[kc] = *(const f16x8*)(XL + o);
          }
        }
        const int part = pu >> 1, sub = pu & 1;
        const int rowbase = part*128 + h*32 + sub*16;
        const u16* wph = WIh + (size_t)((h*6 + pu)*4)*512 + ln*8;
        const u16* wpl = WIl + (size_t)((h*6 + pu)*4)*512 + ln*8;
        f32x4 aH = (f32x4){0.f,0.f,0.f,0.f};
        f32x4 aC = (f32x4){0.f,0.f,0.f,0.f};
        #pragma unroll
        for (int kc = 0; kc < 4; ++kc) {
          const f16x8 Ah = *(const f16x8*)(wph + kc*512);
          const f16x8 Al = *(const f16x8*)(wpl + kc*512);
          aH = __builtin_amdgcn_mfma_f32_16x16x32_f16(Ah, Bh[kc], aH, 0,0,0);
          aC = __builtin_amdgcn_mfma_f32_16x16x32_f16(Ah, Bl[kc], aC, 0,0,0);
          aC = __builtin_amdgcn_mfma_f32_16x16x32_f16(Al, Bh[kc], aC, 0,0,0);
        }
        const float4 bia = *(const float4*)(in_b + rowbase + lg*4);
        const float v0 = aH[0] + aC[0]*(1.f/2048.f) + bia.x;
        const float v1 = aH[1] + aC[1]*(1.f/2048.f) + bia.y;
        const float v2 = aH[2] + aC[2]*(1.f/2048.f) + bia.z;
        const float v3 = aH[3] + aC[3]*(1.f/2048.f) + bia.w;
        const int cell = nt*16 + lr;
        if (part < 2) {
          ushort4 hw, lw;
          splitu(v0, hw.x, lw.x); splitu(v1, hw.y, lw.y);
          splitu(v2, hw.z, lw.z); splitu(v3, hw.w, lw.w);
          const int sflat = part*4 + sub*2 + (lg >> 1);
          const int byo   = (lg & 1)*8;
          const uint32_t adH = (uint32_t)cell*256u +
              ((uint32_t)(sflat ^ (cell & 15)) << 4) + byo;
          const uint32_t adL = (uint32_t)cell*256u +
              ((uint32_t)((8 + sflat) ^ (cell & 15)) << 4) + byo;
          *(ushort4*)(QK + adH) = hw;
          *(ushort4*)(QK + adL) = lw;
        } else {
          const float vv[4] = {v0, v1, v2, v3};
          #pragma unroll
          for (int r = 0; r < 4; ++r) {
            const int hd = sub*16 + lg*4 + r;
            u16 hh, llv;
            splitu(vv[r], hh, llv);
            const uint32_t ad = (uint32_t)hd*256u +
                ((uint32_t)((cell >> 3) ^ (hd & 15)) << 4) + (cell & 7)*2;
            *(u16*)(VTH + ad) = hh;
            *(u16*)(VTL + ad) = llv;
          }
        }
      }
    }
    __syncthreads();

    // ---- scores: 36 tiles (6 qt x 6 nt) over 8 waves ----
    {
      const uint32_t mb = (h==0) ? 0xFFu : (h==1) ? 0xFF00u
                        : (h==2) ? 0xFF0000u : 0u;
      const int t0 = (wv*36) >> 3, t1 = ((wv + 1)*36) >> 3;
      for (int t = t0; t < t1; ++t) {
        const int qt = t/6, nt = t - (t/6)*6;
        const int ra = qt*16 + lr;
        const f16x8 Qh = *(const f16x8*)(QK + (uint32_t)ra*256u +
            ((uint32_t)(lg ^ (ra & 15)) << 4));
        const f16x8 Ql = *(const f16x8*)(QK + (uint32_t)ra*256u +
            ((uint32_t)((8 + lg) ^ (ra & 15)) << 4));
        const int rb = nt*16 + lr;
        const f16x8 Kh = *(const f16x8*)(QK + (uint32_t)rb*256u +
            ((uint32_t)((4 + lg) ^ (rb & 15)) << 4));
        const f16x8 Kl = *(const f16x8*)(QK + (uint32_t)rb*256u +
            ((uint32_t)((12 + lg) ^ (rb & 15)) << 4));
        f32x4 aH = (f32x4){0.f,0.f,0.f,0.f};
        f32x4 aC = (f32x4){0.f,0.f,0.f,0.f};
        aH = __builtin_amdgcn_mfma_f32_16x16x32_f16(Qh, Kh, aH, 0,0,0);
        aC = __builtin_amdgcn_mfma_f32_16x16x32_f16(Qh, Kl, aC, 0,0,0);
        aC = __builtin_amdgcn_mfma_f32_16x16x32_f16(Ql, Kh, aC, 0,0,0);
        const int kcell = nt*16 + lr;
        const uint32_t kk = RCB[kcell];
        #pragma unroll
        for (int r = 0; r < 4; ++r) {
          const int q = qt*16 + lg*4 + r;
          const uint32_t qq = RCB[q];
          const float msk = (((qq ^ kk) & mb) == 0u) ? 1.f : 0.f;
          SC[q*132 + kcell] =
              (aH[r] + aC[r]*(1.f/2048.f)) * 0.17677669529663687f + msk;
        }
      }
    }
    __syncthreads();

    // ---- softmax (e in regs) + P hi/lo write + asc fold ----
    float e[24];
    float rinv = 0.f;
    if (tid < 324) {
      const float* sr = SC + srow*132 + ssub*24;
      #pragma unroll
      for (int q4 = 0; q4 < 6; ++q4) {
        const float4 v = *(const float4*)(sr + q4*4);
        e[q4*4+0] = v.x; e[q4*4+1] = v.y; e[q4*4+2] = v.z; e[q4*4+3] = v.w;
      }
      float m = -1e30f;
      #pragma unroll
      for (int c = 0; c < 24; ++c)
        if (c < skn) m = fmaxf(m, e[c]);
      m = fmaxf(m, __shfl_xor(m, 1));
      m = fmaxf(m, __shfl_xor(m, 2));
      float ss = 0.f;
      #pragma unroll
      for (int c = 0; c < 24; ++c) {
        const float ex = (c < skn) ? __expf(e[c] - m) : 0.f;
        e[c] = ex;
        ss += ex;
      }
      ss += __shfl_xor(ss, 1);
      ss += __shfl_xor(ss, 2);
      rinv = 1.0f / ss;
    }
    __syncthreads();   // all SC reads done before P (aliasing SC) is written
    if (tid < 324) {
      #pragma unroll
      for (int cc = 0; cc < 3; ++cc) {
        const int c8 = ssub*3 + cc;
        union { u16 u[8]; uint4 v; } hw, lw;
        #pragma unroll
        for (int j = 0; j < 8; ++j) {
          const float p = e[cc*8 + j] * rinv;   // pads already zero
          ascR[cc*8 + j] += p;
          splitu(p, hw.u[j], lw.u[j]);
        }
        const uint32_t ad = (uint32_t)srow*256u +
            ((uint32_t)(c8 ^ (srow & 15)) << 4);
        *(uint4*)(PH + ad) = hw.v;
        *(uint4*)(PL + ad) = lw.v;
      }
    }
    __syncthreads();

    // ---- PV: ctx[cell][hd] = V^T · P : 12 tiles (2 ot x 6 nt) ----
    for (int t = wv; t < 12; t += 8) {
      const int ot = t/6, nt = t - (t/6)*6;
      f32x4 aH = (f32x4){0.f,0.f,0.f,0.f};
      f32x4 aC = (f32x4){0.f,0.f,0.f,0.f};
      #pragma unroll
      for (int kc = 0; kc < 3; ++kc) {
        const int ra = ot*16 + lr;
        const uint32_t oa = (uint32_t)ra*256u +
            ((uint32_t)((kc*4 + lg) ^ (ra & 15)) << 4);
        const f16x8 Vh = *(const f16x8*)(VTH + oa);
        const f16x8 Vl = *(const f16x8*)(VTL + oa);
        const int rb = nt*16 + lr;
        const uint32_t ob = (uint32_t)rb*256u +
            ((uint32_t)((kc*4 + lg) ^ (rb & 15)) << 4);
        const f16x8 Pf  = *(const f16x8*)(PH + ob);
        const f16x8 Pl2 = *(const f16x8*)(PL + ob);
        aH = __builtin_amdgcn_mfma_f32_16x16x32_f16(Vh, Pf,  aH, 0,0,0);
        aC = __builtin_amdgcn_mfma_f32_16x16x32_f16(Vh, Pl2, aC, 0,0,0);
        aC = __builtin_amdgcn_mfma_f32_16x16x32_f16(Vl, Pf,  aC, 0,0,0);
      }
      const int cell = nt*16 + lr;
      if (cell < 81) {
        const size_t co = ((size_t)b*81 + cell)*128 + h*32 + ot*16 + lg*4;
        ushort4 hw, lw;
        float r0 = aH[0] + aC[0]*(1.f/2048.f);
        float r1 = aH[1] + aC[1]*(1.f/2048.f);
        float r2 = aH[2] + aC[2]*(1.f/2048.f);
        float r3 = aH[3] + aC[3]*(1.f/2048.f);
        splitu(r0, hw.x, lw.x); splitu(r1, hw.y, lw.y);
        splitu(r2, hw.z, lw.z); splitu(r3, hw.w, lw.w);
        *(ushort4*)(ctxh + co) = hw;
        *(ushort4*)(ctxl + co) = lw;
      }
    }
    __syncthreads();
  } // heads

  // asc = mean over heads (softmax-thread ownership)
  if (tid < 324) {
    float* ap = asc + (size_t)b*6561 + srow*81 + ssub*24;
    #pragma unroll
    for (int c = 0; c < 24; ++c)
      if (c < skn) ap[c] = 0.25f * ascR[c];
  }
}

// ---------------- post (MFMA): out-proj -> LN -> l1 -> l2 -> heads ---------
#define POST_LDS_BYTES 105664

__global__ __launch_bounds__(512, 1) void k_post(
    const u16* __restrict__ ctxh, const u16* __restrict__ ctxl,
    const u16* __restrict__ WOh,  const float* __restrict__ out_b,
    const float* __restrict__ ln_g, const float* __restrict__ ln_b,
    const u16* __restrict__ W1h,  const float* __restrict__ l1_b,
    const u16* __restrict__ W2h,  const float* __restrict__ l2_b,
    const float* __restrict__ pos_w, const float* __restrict__ pos_b,
    const float* __restrict__ num_w, const float* __restrict__ num_b,
    const int* __restrict__ digits,  float* __restrict__ dout)
{
  extern __shared__ char smc[];
  char*  YH   = smc;
  char*  YL   = smc + 24576;
  char*  ZH   = smc + 49152;
  char*  ZL   = smc + 73728;
  float* red1 = (float*)(smc + 98304);
  float* red2 = (float*)(smc + 101376);
  float* mu   = (float*)(smc + 104448);
  float* rstd = (float*)(smc + 104832);
  float* vals = (float*)(smc + 105216);
  int*   posi = (int*)(smc + 105600);

  const int b   = blockIdx.x;
  const int tid = threadIdx.x;
  const int ln  = tid & 63;
  const int wv  = tid >> 6;
  const int lg  = ln >> 4;
  const int lr  = ln & 15;
  const int ocb = wv*16 + lg*4;

  // ---- stage ctx -> YH/YL, zero pad rows ----
  {
    const u16* gh = ctxh + (size_t)b*81*128;
    const u16* gl = ctxl + (size_t)b*81*128;
    for (int i = tid; i < 1296; i += 512) {
      const int n = i >> 4, k8 = i & 15;
      const uint4 hv = *(const uint4*)(gh + n*128 + k8*8);
      const uint4 lv = *(const uint4*)(gl + n*128 + k8*8);
      const uint32_t bo = (uint32_t)n*256u + ((uint32_t)(k8 ^ (n & 15)) << 4);
      *(uint4*)(YH + bo) = hv;
      *(uint4*)(YL + bo) = lv;
    }
    for (int i = tid; i < 480; i += 512) {
      char* base = (i < 240) ? YH : YL;
      const int j = (i < 240) ? i : (i - 240);
      *(uint4*)(base + 81*256 + j*16) = make_uint4(0u,0u,0u,0u);
    }
  }
  __syncthreads();

  f32x4 aH[6], aC[6];
  #define GEMM6(BH, BL, WT)                                               \
    {                                                                     \
      _Pragma("unroll")                                                   \
      for (int nt = 0; nt < 6; ++nt) {                                    \
        aH[nt] = (f32x4){0.f,0.f,0.f,0.f};                                \
        aC[nt] = (f32x4){0.f,0.f,0.f,0.f};                                \
      }                                                                   \
      for (int kc = 0; kc < 4; ++kc) {                                    \
        const int ab = ((kc*8 + wv)*64 + ln)*8;                           \
        const f16x8 Ah = *(const f16x8*)((WT) + ab);                      \
        const f16x8 Al = *(const f16x8*)((WT) + 16384 + ab);              \
        _Pragma("unroll")                                                 \
        for (int nt = 0; nt < 6; ++nt) {                                  \
          const int row = nt*16 + lr;                                     \
          const uint32_t o = (uint32_t)row*256u +                         \
              ((uint32_t)((kc*4 + lg) ^ (row & 15)) << 4);                \
          const f16x8 Bh = *(const f16x8*)((BH) + o);                     \
          const f16x8 Bl = *(const f16x8*)((BL) + o);                     \
          aH[nt] = __builtin_amdgcn_mfma_f32_16x16x32_f16(Ah, Bh, aH[nt], 0,0,0); \
          aC[nt] = __builtin_amdgcn_mfma_f32_16x16x32_f16(Ah, Bl, aC[nt], 0,0,0); \
          aC[nt] = __builtin_amdgcn_mfma_f32_16x16x32_f16(Al, Bh, aC[nt], 0,0,0); \
        }                                                                 \
      }                                                                   \
    }

  // ---- out projection ----
  GEMM6(YH, YL, WOh);
  float y[6][4];
  {
    const float4 bv = *(const float4*)(out_b + ocb);
    #pragma unroll
    for (int nt = 0; nt < 6; ++nt) {
      y[nt][0] = aH[nt][0] + aC[nt][0]*(1.f/2048.f) + bv.x;
      y[nt][1] = aH[nt][1] + aC[nt][1]*(1.f/2048.f) + bv.y;
      y[nt][2] = aH[nt][2] + aC[nt][2]*(1.f/2048.f) + bv.z;
      y[nt][3] = aH[nt][3] + aC[nt][3]*(1.f/2048.f) + bv.w;
    }
  }

  // ---- LayerNorm over oc, two-pass ----
  #pragma unroll
  for (int nt = 0; nt < 6; ++nt) {
    float s1 = y[nt][0] + y[nt][1] + y[nt][2] + y[nt][3];
    s1 += __shfl_xor(s1, 16);
    s1 += __shfl_xor(s1, 32);
    if (ln < 16) red1[(nt*16 + lr)*8 + wv] = s1;
  }
  __syncthreads();
  if (tid < 96) {
    float s = 0.f;
    #pragma unroll
    for (int w = 0; w < 8; ++w) s += red1[tid*8 + w];
    mu[tid] = s * (1.0f/128.0f);
  }
  __syncthreads();
  #pragma unroll
  for (int nt = 0; nt < 6; ++nt) {
    const float m = mu[nt*16 + lr];
    float d0 = y[nt][0]-m, d1 = y[nt][1]-m, d2 = y[nt][2]-m, d3 = y[nt][3]-m;
    float s2 = d0*d0 + d1*d1 + d2*d2 + d3*d3;
    s2 += __shfl_xor(s2, 16);
    s2 += __shfl_xor(s2, 32);
    if (ln < 16) red2[(nt*16 + lr)*8 + wv] = s2;
  }
  __syncthreads();
  if (tid < 96) {
    float s = 0.f;
    #pragma unroll
    for (int w = 0; w < 8; ++w) s += red2[tid*8 + w];
    rstd[tid] = 1.0f / sqrtf(s * (1.0f/128.0f) + 1e-5f);
  }
  __syncthreads();
  {
    const float4 g  = *(const float4*)(ln_g + ocb);
    const float4 bb = *(const float4*)(ln_b + ocb);
    #pragma unroll
    for (int nt = 0; nt < 6; ++nt) {
      const int cell = nt*16 + lr;
      const float m = mu[cell], rs = rstd[cell];
      float z0 = (y[nt][0]-m)*rs*g.x + bb.x;
      float z1 = (y[nt][1]-m)*rs*g.y + bb.y;
      float z2 = (y[nt][2]-m)*rs*g.z + bb.z;
      float z3 = (y[nt][3]-m)*rs*g.w + bb.w;
      ushort4 hw, lw;
      splitu(z0, hw.x, lw.x); splitu(z1, hw.y, lw.y);
      splitu(z2, hw.z, lw.z); splitu(z3, hw.w, lw.w);
      const uint32_t ad = (uint32_t)cell*256u +
          ((uint32_t)((wv*2 + (lg >> 1)) ^ (cell & 15)) << 4) + (lg & 1)*8;
      *(ushort4*)(ZH + ad) = hw;
      *(ushort4*)(ZL + ad) = lw;
    }
  }
  __syncthreads();

  // ---- l1 (silu): reads ZH/ZL, writes YH/YL ----
  GEMM6(ZH, ZL, W1h);
  {
    const float4 bv = *(const float4*)(l1_b + ocb);
    #pragma unroll
    for (int nt = 0; nt < 6; ++nt) {
      const int cell = nt*16 + lr;
      float z0 = silu_f(aH[nt][0] + aC[nt][0]*(1.f/2048.f) + bv.x);
      float z1 = silu_f(aH[nt][1] + aC[nt][1]*(1.f/2048.f) + bv.y);
      float z2 = silu_f(aH[nt][2] + aC[nt][2]*(1.f/2048.f) + bv.z);
      float z3 = silu_f(aH[nt][3] + aC[nt][3]*(1.f/2048.f) + bv.w);
      ushort4 hw, lw;
      splitu(z0, hw.x, lw.x); splitu(z1, hw.y, lw.y);
      splitu(z2, hw.z, lw.z); splitu(z3, hw.w, lw.w);
      const uint32_t ad = (uint32_t)cell*256u +
          ((uint32_t)((wv*2 + (lg >> 1)) ^ (cell & 15)) << 4) + (lg & 1)*8;
      *(ushort4*)(YH + ad) = hw;
      *(ushort4*)(YL + ad) = lw;
    }
  }
  __syncthreads();

  // ---- l2 (silu): reads YH/YL, writes ZH/ZL; pos partials fused ----
  GEMM6(YH, YL, W2h);
  {
    const float4 bv = *(const float4*)(l2_b + ocb);
    const float4 pw = *(const float4*)(pos_w + ocb);
    #pragma unroll
    for (int nt = 0; nt < 6; ++nt) {
      const int cell = nt*16 + lr;
      float z0 = silu_f(aH[nt][0] + aC[nt][0]*(1.f/2048.f) + bv.x);
      float z1 = silu_f(aH[nt][1] + aC[nt][1]*(1.f/2048.f) + bv.y);
      float z2 = silu_f(aH[nt][2] + aC[nt][2]*(1.f/2048.f) + bv.z);
      float z3 = silu_f(aH[nt][3] + aC[nt][3]*(1.f/2048.f) + bv.w);
      ushort4 hw, lw;
      splitu(z0, hw.x, lw.x); splitu(z1, hw.y, lw.y);
      splitu(z2, hw.z, lw.z); splitu(z3, hw.w, lw.w);
      const uint32_t ad = (uint32_t)cell*256u +
          ((uint32_t)((wv*2 + (lg >> 1)) ^ (cell & 15)) << 4) + (lg & 1)*8;
      *(ushort4*)(ZH + ad) = hw;
      *(ushort4*)(ZL + ad) = lw;
      float ps = z0*pw.x + z1*pw.y + z2*pw.z + z3*pw.w;
      ps += __shfl_xor(ps, 16);
      ps += __shfl_xor(ps, 32);
      if (ln < 16) red1[cell*8 + wv] = ps;
    }
  }
  __syncthreads();

  // ---- position head + gumbel sampling ----
  uint32_t k1a, k1b, k2a, k2b;
  jax_split42(k1a, k1b, k2a, k2b);

  if (tid < 81) {
    float acc = pos_b[0];
    #pragma unroll
    for (int w = 0; w < 8; ++w) acc += red1[tid*8 + w];
    if (digits[b*81 + tid] != 0) acc = -1e9f;
    uint32_t bits = jax_randbits(k1a, k1b, (uint32_t)(b*81 + tid));
    vals[tid] = acc + jax_gumbel_bits(bits);
  }
  __syncthreads();
  if (tid == 0) {
    float best = vals[0]; int bi = 0;
    for (int n = 1; n < 81; ++n)
      if (vals[n] > best) { best = vals[n]; bi = n; }
    *posi = bi;
    dout[b] = (float)bi;
  }
  __syncthreads();
  const int pos = *posi;

  // ---- number head at sampled position ----
  if (tid < 80) {
    const int d = tid >> 3, j = tid & 7;
    float ssum = 0.f;
    #pragma unroll
    for (int c = 0; c < 16; ++c) {
      const int k = j*16 + c;
      const uint32_t ad = (uint32_t)pos*256u +
          ((uint32_t)((k >> 3) ^ (pos & 15)) << 4) + (k & 7)*2;
      const float yv = joinu(*(const u16*)(ZH + ad), *(const u16*)(ZL + ad));
      ssum += yv * num_w[d*128 + k];
    }
    red2[tid] = ssum;
  }
  __syncthreads();
  if (tid < 10) {
    float acc = num_b[tid];
    #pragma unroll
    for (int j = 0; j < 8; ++j) acc += red2[tid*8 + j];
    if (tid == 0) acc = -INFINITY;
    uint32_t bits = jax_randbits(k2a, k2b, (uint32_t)(b*10 + tid));
    vals[tid] = acc + jax_gumbel_bits(bits);
  }
  __syncthreads();
  if (tid == 0) {
    float best = vals[0]; int bi = 0;
    for (int d = 1; d < 10; ++d)
      if (vals[d] > best) { best = vals[d]; bi = d; }
    dout[NB + b] = (float)bi;
  }
}

// ---------------------------------------------------------------------------
extern "C" void kernel_launch(void* const* d_in, const int* in_sizes, int n_in,
                              void* d_out, int out_size, void* d_ws, size_t ws_size,
                              hipStream_t stream) {
  const float* s     = (const float*)d_in[0];
  const float* c1_w  = (const float*)d_in[1];
  const float* c1_b  = (const float*)d_in[2];
  const float* c2_w  = (const float*)d_in[3];
  const float* c2_b  = (const float*)d_in[4];
  const float* c3_w  = (const float*)d_in[5];
  const float* c3_b  = (const float*)d_in[6];
  const float* emb   = (const float*)d_in[7];
  const float* in_w  = (const float*)d_in[8];
  const float* in_b  = (const float*)d_in[9];
  const float* out_w = (const float*)d_in[10];
  const float* out_b = (const float*)d_in[11];
  const float* ln_g  = (const float*)d_in[12];
  const float* ln_b  = (const float*)d_in[13];
  const float* l1_w  = (const float*)d_in[14];
  const float* l1_b  = (const float*)d_in[15];
  const float* l2_w  = (const float*)d_in[16];
  const float* l2_b  = (const float*)d_in[17];
  const float* pos_w = (const float*)d_in[18];
  const float* pos_b = (const float*)d_in[19];
  const float* num_w = (const float*)d_in[20];
  const float* num_b = (const float*)d_in[21];

  // ws layout (floats):
  // T2e 0 (12672) | WAh 12672 | WAl 86400 | WOh 160128 | W1h 176512 |
  // W2h 192896 | WIh 209280 (24576) | WIl 233856 (24576) | digits 258432 |
  // xh 541056 (u16) | xl 21774720 (u16) | ctxh 43008384 (u16) | ctxl +half
  float* ws     = (float*)d_ws;
  float* T2e    = ws;
  u16*   WAh    = (u16*)(ws + 12672);
  u16*   WAl    = (u16*)(ws + 86400);
  u16*   WOh    = (u16*)(ws + 160128);
  u16*   W1h    = (u16*)(ws + 176512);
  u16*   W2h    = (u16*)(ws + 192896);
  u16*   WIh    = (u16*)(ws + 209280);
  u16*   WIl    = (u16*)(ws + 233856);
  int*   digits = (int*)(ws + 258432);
  u16*   xh     = (u16*)(ws + 541056);
  u16*   xl     = (u16*)(ws + 21774720);
  u16*   ctxh   = (u16*)(ws + 43008384);
  u16*   ctxl   = (u16*)(ws + 43008384 + 21233664);

  float* dout = (float*)d_out;
  float* asc  = dout + 2*NB;

  hipFuncSetAttribute((const void*)k_attn,
                      hipFuncAttributeMaxDynamicSharedMemorySize,
                      ATTN_LDS_BYTES);
  hipFuncSetAttribute((const void*)k_post,
                      hipFuncAttributeMaxDynamicSharedMemorySize,
                      POST_LDS_BYTES);

  k_prep<<<dim3(1010), dim3(256), 0, stream>>>(
      c1_w, c1_b, c2_w, c3_w, in_w, out_w, l1_w, l2_w,
      T2e, WAh, WAl, WIh, WIl, WOh, W1h, W2h);
  k_stem<<<dim3(NB), dim3(256), 0, stream>>>(
      s, T2e, c2_b, WAh, WAl, c3_b, emb, xh, xl, digits);
  k_attn<<<dim3(NB), dim3(512), ATTN_LDS_BYTES, stream>>>(
      xh, xl, WIh, WIl, in_b, ctxh, ctxl, asc);
  k_post<<<dim3(NB), dim3(512), POST_LDS_BYTES, stream>>>(
      ctxh, ctxl, WOh, out_b, ln_g, ln_b, W1h, l1_b, W2h, l2_b,
      pos_w, pos_b, num_w, num_b, digits, dout);
}